// Round 5
// baseline (702.368 us; speedup 1.0000x reference)
//
#include <hip/hip_runtime.h>
#include <hip/hip_bf16.h>

#define IN_F   4096
#define OUT_F  4096
#define NTOK   8192
#define LRANK  128

typedef unsigned short u16;
typedef __attribute__((ext_vector_type(8))) __bf16 bf16x8;
typedef __attribute__((ext_vector_type(4))) float f32x4;

__device__ __forceinline__ u16 f2bf(float f) {
  union { float f; unsigned u; } a; a.f = f;
  return (u16)((a.u + 0x7fffu + ((a.u >> 16) & 1u)) >> 16);
}

// async global->LDS, 16B per lane. LDS dest is wave-uniform base + lane*16.
__device__ __forceinline__ void async_ld16(const void* g, void* l) {
  __builtin_amdgcn_global_load_lds(
      (__attribute__((address_space(1))) void*)(unsigned long long)g,
      (__attribute__((address_space(3))) void*)(unsigned int)(unsigned long long)l,
      16, 0, 0);
}

// Stage one half-tile: 128 rows x 64 cols bf16 of row-major [*,stride] matrix
// into a 16 KiB LDS region, XOR-swizzled (T2) via pre-permuted GLOBAL source:
// dest chunk (row, slot) receives logical chunk (row, slot ^ (row&7)).
// 512 threads x 2 loads x 16B. LDS dest = wave-uniform base + lane*16.
__device__ __forceinline__ void stage_half(const u16* __restrict__ g, int stride,
                                           int row0, int col0, u16* ldsb, int tid) {
#pragma unroll
  for (int p = 0; p < 2; ++p) {
    int cbase = (tid & ~63) + (p << 9);       // wave-uniform chunk base
    int c = cbase + (tid & 63);               // chunk in [0,1024)
    int row = c >> 3, slot = c & 7;
    const u16* src = g + (size_t)(row0 + row) * stride + col0 + ((slot ^ (row & 7)) << 3);
    async_ld16(src, (char*)ldsb + (size_t)cbase * 16);
  }
}

// Swizzled frag read from a [128][64] bf16 half-tile region.
// logical: row r, k-slice ks (0/1), lane's 8 elems at k = ks*32+(lane>>4)*8.
__device__ __forceinline__ bf16x8 ld_frag(const u16* half_base, int r, int ks, int lane) {
  int byte = (r << 7) + (ks << 6) + ((lane >> 4) << 4);
  byte ^= (r & 7) << 4;
  return *(const bf16x8*)((const char*)half_base + byte);
}

// ---------------- prep kernels ----------------

__global__ void cvt_bf16_kernel(const float* __restrict__ src, u16* __restrict__ dst, int n4) {
  int i = blockIdx.x * blockDim.x + threadIdx.x;
  if (i >= n4) return;
  float4 v = ((const float4*)src)[i];
  ushort4 o;
  o.x = f2bf(v.x); o.y = f2bf(v.y); o.z = f2bf(v.z); o.w = f2bf(v.w);
  ((ushort4*)dst)[i] = o;
}

__global__ void dequant_kernel(const int* __restrict__ zm, const float* __restrict__ cb,
                               const float* __restrict__ gs, const float* __restrict__ gb,
                               u16* __restrict__ W) {
  int idx = blockIdx.x * blockDim.x + threadIdx.x;   // one thread per 4 weights
  if (idx >= OUT_F * IN_F / 4) return;
  int o = idx >> 10;
  int i = (idx & 1023) << 2;
  int row = ((o >> 6) << 6) + (i >> 6);
  const int* zp = zm + ((size_t)row << 12) + ((o & 63) << 6) + (i & 63);
  int4 z = *(const int4*)zp;
  const float* cr = cb + ((size_t)row << 8);
  int g = (o >> 3) * (IN_F / 8) + (i >> 3);
  float s = gs[g], b = gb[g];
  ushort4 w;
  w.x = f2bf(b + cr[z.x] * s);
  w.y = f2bf(b + cr[z.y] * s);
  w.z = f2bf(b + cr[z.z] * s);
  w.w = f2bf(b + cr[z.w] * s);
  *(ushort4*)(W + (size_t)idx * 4) = w;
}

// ---------------- hid GEMM (unchanged, correct) ----------------

__device__ __forceinline__ void stage_tile_128x32(const u16* __restrict__ g, int stride,
                                                  int row0, int col0,
                                                  u16* lbase, int wave, int lane) {
#pragma unroll
  for (int p = 0; p < 2; ++p) {
    int li_base = wave * 64 + p * 256;
    int li = li_base + lane;
    const u16* gaddr = g + (size_t)(row0 + (li >> 2)) * stride + col0 + ((li & 3) << 3);
    async_ld16(gaddr, lbase + li_base * 8);
  }
}

__global__ __launch_bounds__(256) void gemm_hid(const u16* __restrict__ A,
                                                const u16* __restrict__ L1,
                                                u16* __restrict__ H) {
  __shared__ __align__(16) u16 lds[2 * 128 * 32];
  u16* ldsA = lds;
  u16* ldsB = lds + 128 * 32;

  int tid = threadIdx.x;
  int wave = tid >> 6, lane = tid & 63;
  int bm0 = blockIdx.x * 128;
  int wr = (wave >> 1) * 64, wc = (wave & 1) * 64;
  int lrow = lane & 15, lk = (lane >> 4) * 8;

  f32x4 acc[4][4];
#pragma unroll
  for (int m = 0; m < 4; ++m)
#pragma unroll
    for (int n = 0; n < 4; ++n)
#pragma unroll
      for (int v = 0; v < 4; ++v) acc[m][n][v] = 0.f;

  for (int kt = 0; kt < IN_F / 32; ++kt) {
    int k0 = kt * 32;
    stage_tile_128x32(A, IN_F, bm0, k0, ldsA, wave, lane);
    stage_tile_128x32(L1, IN_F, 0, k0, ldsB, wave, lane);
    __syncthreads();
    bf16x8 af[4], bfr[4];
#pragma unroll
    for (int m = 0; m < 4; ++m)
      af[m] = *(const bf16x8*)&ldsA[(wr + m * 16 + lrow) * 32 + lk];
#pragma unroll
    for (int n = 0; n < 4; ++n)
      bfr[n] = *(const bf16x8*)&ldsB[(wc + n * 16 + lrow) * 32 + lk];
#pragma unroll
    for (int m = 0; m < 4; ++m)
#pragma unroll
      for (int n = 0; n < 4; ++n)
        acc[m][n] = __builtin_amdgcn_mfma_f32_16x16x32_bf16(af[m], bfr[n], acc[m][n], 0, 0, 0);
    __syncthreads();
  }

  int lrow4 = (lane >> 4) * 4;
#pragma unroll
  for (int m = 0; m < 4; ++m)
#pragma unroll
    for (int n = 0; n < 4; ++n)
#pragma unroll
      for (int v = 0; v < 4; ++v) {
        int rg = bm0 + wr + m * 16 + lrow4 + v;
        int cg = wc + n * 16 + lrow;
        H[(size_t)rg * LRANK + cg] = f2bf(acc[m][n][v]);
      }
}

// ---------------- main GEMM: 256x256 tile, BK=64, 8-phase schedule ----------------
// buf0 holds even K-tiles, buf1 odd. Stage ledger (per iter u; kt c0=2u, c1=2u+1,
// n0=2u+2, n1=2u+3):  P1: buf1.A-h0<-c1  P2: buf1.A-h1<-c1  P3: buf0.B-h0<-n0
// P4: buf0.B-h1<-n0 +vmcnt(4)  P5: buf0.A-h0<-n0  P6: buf0.A-h1<-n0
// P7: buf1.B-h0<-n1  P8: buf1.B-h1<-n1 +vmcnt(4).
// Deadness: B dies after phase 2/6 (nh0 kept in regs), A after 3/7.

#define MFMA_QUAD(mh, nh)                                                        \
  _Pragma("unroll") for (int mf = 0; mf < 4; ++mf)                               \
  _Pragma("unroll") for (int nf = 0; nf < 2; ++nf)                               \
  _Pragma("unroll") for (int ks = 0; ks < 2; ++ks)                               \
    acc[(mh)*4 + mf][(nh)*2 + nf] = __builtin_amdgcn_mfma_f32_16x16x32_bf16(     \
        af[mf][ks], bfr[nh][nf][ks], acc[(mh)*4 + mf][(nh)*2 + nf], 0, 0, 0);

#define PHASE_MID                                          \
  __builtin_amdgcn_s_barrier();                            \
  asm volatile("s_waitcnt lgkmcnt(0)" ::: "memory");       \
  __builtin_amdgcn_sched_barrier(0);                       \
  __builtin_amdgcn_s_setprio(1);

#define PHASE_END                                          \
  __builtin_amdgcn_s_setprio(0);                           \
  __builtin_amdgcn_s_barrier();

#define PHASE_END_VM                                       \
  __builtin_amdgcn_s_setprio(0);                           \
  asm volatile("s_waitcnt vmcnt(4)" ::: "memory");         \
  __builtin_amdgcn_s_barrier();

// waves_per_eu(2,2): LDS (128 KiB) already limits to 1 block/CU = 2 waves/EU;
// pinning min=max=2 sets the register allocator budget to 512/2 = 256 regs/lane
// so acc[8][4] (128) + fragments (64) + addressing fit WITHOUT scratch spill.
__global__ __launch_bounds__(512)
__attribute__((amdgpu_waves_per_eu(2, 2)))
void gemm_main(const u16* __restrict__ A,
               const u16* __restrict__ W,
               const u16* __restrict__ H,
               const u16* __restrict__ L2,
               const float* __restrict__ scale,
               const float* __restrict__ bias,
               float* __restrict__ out) {
  __shared__ __align__(16) u16 lds[65536];   // 128 KiB

  const int tid = threadIdx.x;
  const int lane = tid & 63, wave = tid >> 6;
  const int wg_m = wave >> 2, wg_n = wave & 3;
  const int lr = lane & 15;

  // bijective XCD swizzle (nwg=512, 512%8==0)
  int bid = blockIdx.x;
  int swz = (bid & 7) * 64 + (bid >> 3);
  const int bn0 = (swz & 15) * 256;
  const int bm0 = (swz >> 4) * 256;

  // LDS regions (u16 units): buf b at b*32768; A halves +0,+8192; B halves +16384,+24576
#define LA(b, h) (lds + (b) * 32768 + (h) * 8192)
#define LB(b, h) (lds + (b) * 32768 + 16384 + (h) * 8192)

  const int b_half = wg_n >> 1;            // wave's B storage half
  const int b_row0 = (wg_n & 1) * 64;      // row base within that half

  f32x4 acc[8][4];
#pragma unroll
  for (int m = 0; m < 8; ++m)
#pragma unroll
    for (int n = 0; n < 4; ++n)
#pragma unroll
      for (int v = 0; v < 4; ++v) acc[m][n][v] = 0.f;

  // ---- prologue: kt0 -> buf0 (B0,B1,A0,A1), kt1.B -> buf1 ----
  stage_half(W, IN_F, bn0 + 0,   0, LB(0, 0), tid);
  stage_half(W, IN_F, bn0 + 128, 0, LB(0, 1), tid);
  stage_half(A, IN_F, bm0 + 0,   0, LA(0, 0), tid);
  stage_half(A, IN_F, bm0 + 128, 0, LA(0, 1), tid);
  stage_half(W, IN_F, bn0 + 0,   64, LB(1, 0), tid);
  stage_half(W, IN_F, bn0 + 128, 64, LB(1, 1), tid);
  asm volatile("s_waitcnt vmcnt(4)" ::: "memory");   // kt0 landed; kt1.B may fly
  __builtin_amdgcn_s_barrier();

  bf16x8 af[4][2];        // current A m-half (4 m-frags x 2 k-slices)
  bf16x8 bfr[2][2][2];    // both B n-halves kept ([nh][nf][ks])

  for (int u = 0; u < 32; ++u) {
    const int c1k = (2 * u + 1) * 64;
    const int n0  = 2 * u + 2, n1 = 2 * u + 3;
    const int n0k = (n0 > 63 ? 63 : n0) * 64;
    const int n1k = (n1 > 63 ? 63 : n1) * 64;

    // ---- P1: quad(0,0) on buf0 ----
#pragma unroll
    for (int mf = 0; mf < 4; ++mf)
#pragma unroll
      for (int ks = 0; ks < 2; ++ks)
        af[mf][ks] = ld_frag(LA(0, wg_m), mf * 16 + lr, ks, lane);
#pragma unroll
    for (int nf = 0; nf < 2; ++nf)
#pragma unroll
      for (int ks = 0; ks < 2; ++ks)
        bfr[0][nf][ks] = ld_frag(LB(0, b_half), b_row0 + nf * 16 + lr, ks, lane);
    stage_half(A, IN_F, bm0 + 0, c1k, LA(1, 0), tid);
    PHASE_MID; MFMA_QUAD(0, 0); PHASE_END;

    // ---- P2: quad(0,1) ----
#pragma unroll
    for (int nf = 0; nf < 2; ++nf)
#pragma unroll
      for (int ks = 0; ks < 2; ++ks)
        bfr[1][nf][ks] = ld_frag(LB(0, b_half), b_row0 + 32 + nf * 16 + lr, ks, lane);
    stage_half(A, IN_F, bm0 + 128, c1k, LA(1, 1), tid);
    PHASE_MID; MFMA_QUAD(0, 1); PHASE_END;

    // ---- P3: quad(1,1) ----
#pragma unroll
    for (int mf = 0; mf < 4; ++mf)
#pragma unroll
      for (int ks = 0; ks < 2; ++ks)
        af[mf][ks] = ld_frag(LA(0, wg_m), 64 + mf * 16 + lr, ks, lane);
    stage_half(W, IN_F, bn0 + 0, n0k, LB(0, 0), tid);
    PHASE_MID; MFMA_QUAD(1, 1); PHASE_END;

    // ---- P4: quad(1,0) (all regs) ----
    stage_half(W, IN_F, bn0 + 128, n0k, LB(0, 1), tid);
    PHASE_MID; MFMA_QUAD(1, 0); PHASE_END_VM;

    // ---- P5: quad(0,0) on buf1 ----
#pragma unroll
    for (int mf = 0; mf < 4; ++mf)
#pragma unroll
      for (int ks = 0; ks < 2; ++ks)
        af[mf][ks] = ld_frag(LA(1, wg_m), mf * 16 + lr, ks, lane);
#pragma unroll
    for (int nf = 0; nf < 2; ++nf)
#pragma unroll
      for (int ks = 0; ks < 2; ++ks)
        bfr[0][nf][ks] = ld_frag(LB(1, b_half), b_row0 + nf * 16 + lr, ks, lane);
    stage_half(A, IN_F, bm0 + 0, n0k, LA(0, 0), tid);
    PHASE_MID; MFMA_QUAD(0, 0); PHASE_END;

    // ---- P6: quad(0,1) ----
#pragma unroll
    for (int nf = 0; nf < 2; ++nf)
#pragma unroll
      for (int ks = 0; ks < 2; ++ks)
        bfr[1][nf][ks] = ld_frag(LB(1, b_half), b_row0 + 32 + nf * 16 + lr, ks, lane);
    stage_half(A, IN_F, bm0 + 128, n0k, LA(0, 1), tid);
    PHASE_MID; MFMA_QUAD(0, 1); PHASE_END;

    // ---- P7: quad(1,1) ----
#pragma unroll
    for (int mf = 0; mf < 4; ++mf)
#pragma unroll
      for (int ks = 0; ks < 2; ++ks)
        af[mf][ks] = ld_frag(LA(1, wg_m), 64 + mf * 16 + lr, ks, lane);
    stage_half(W, IN_F, bn0 + 0, n1k, LB(1, 0), tid);
    PHASE_MID; MFMA_QUAD(1, 1); PHASE_END;

    // ---- P8: quad(1,0) (all regs) ----
    stage_half(W, IN_F, bn0 + 128, n1k, LB(1, 1), tid);
    PHASE_MID; MFMA_QUAD(1, 0); PHASE_END_VM;
  }

  // ---- drain outstanding stages before LDS reuse ----
  asm volatile("s_waitcnt vmcnt(0)" ::: "memory");
  __builtin_amdgcn_s_barrier();

  // ---- fused low-rank epilogue ----
  float scl[4], bs_[4];
#pragma unroll
  for (int nf = 0; nf < 4; ++nf) {
    int cg = bn0 + wg_n * 64 + nf * 16 + lr;
    scl[nf] = scale[cg];
    bs_[nf] = bias[cg];
  }

  // regions: H col-subtile s: lds + s*16384 (+8192 for rows 128-255)
  //          L2 col-subtile s: lds + 32768 + s*16384
  stage_half(H, LRANK, bm0 + 0,   0,  lds + 0,     tid);
  stage_half(H, LRANK, bm0 + 128, 0,  lds + 8192,  tid);
  stage_half(H, LRANK, bm0 + 0,   64, lds + 16384, tid);
  stage_half(H, LRANK, bm0 + 128, 64, lds + 24576, tid);
  stage_half(L2, LRANK, bn0 + 0,   0,  lds + 32768, tid);
  stage_half(L2, LRANK, bn0 + 128, 0,  lds + 40960, tid);
  stage_half(L2, LRANK, bn0 + 0,   64, lds + 49152, tid);
  stage_half(L2, LRANK, bn0 + 128, 64, lds + 57344, tid);
  asm volatile("s_waitcnt vmcnt(0)" ::: "memory");
  __builtin_amdgcn_s_barrier();

  // multiplicative pass: acc *= (H·L2m + scale); macc chunked [4][2] for reg budget
#pragma unroll
  for (int nh = 0; nh < 2; ++nh) {
#pragma unroll
    for (int mh = 0; mh < 2; ++mh) {
      f32x4 macc[4][2];
#pragma unroll
      for (int m = 0; m < 4; ++m)
#pragma unroll
        for (int j = 0; j < 2; ++j)
#pragma unroll
          for (int v = 0; v < 4; ++v) macc[m][j][v] = 0.f;
#pragma unroll
      for (int kc = 0; kc < 4; ++kc) {
        const u16* Hb = lds + (kc >> 1) * 16384;
        const u16* Lb = lds + 32768 + (kc >> 1) * 16384;
        int ks = kc & 1;
        bf16x8 lf[2];
#pragma unroll
        for (int j = 0; j < 2; ++j) {
          int q = wg_n * 64 + (nh * 2 + j) * 16 + lr;
          lf[j] = ld_frag(Lb + (q >> 7) * 8192, q & 127, ks, lane);
        }
#pragma unroll
        for (int mf = 0; mf < 4; ++mf) {
          int q = wg_m * 128 + (mh * 4 + mf) * 16 + lr;
          bf16x8 hf = ld_frag(Hb + (q >> 7) * 8192, q & 127, ks, lane);
          macc[mf][0] = __builtin_amdgcn_mfma_f32_16x16x32_bf16(hf, lf[0], macc[mf][0], 0, 0, 0);
          macc[mf][1] = __builtin_amdgcn_mfma_f32_16x16x32_bf16(hf, lf[1], macc[mf][1], 0, 0, 0);
        }
      }
#pragma unroll
      for (int mf = 0; mf < 4; ++mf)
#pragma unroll
        for (int j = 0; j < 2; ++j)
#pragma unroll
          for (int v = 0; v < 4; ++v)
            acc[mh * 4 + mf][nh * 2 + j][v] *= (macc[mf][j][v] + scl[nh * 2 + j]);
    }
  }

  // restage L2 additive rows
  __builtin_amdgcn_s_barrier();
  stage_half(L2, LRANK, OUT_F + bn0 + 0,   0,  lds + 32768, tid);
  stage_half(L2, LRANK, OUT_F + bn0 + 128, 0,  lds + 40960, tid);
  stage_half(L2, LRANK, OUT_F + bn0 + 0,   64, lds + 49152, tid);
  stage_half(L2, LRANK, OUT_F + bn0 + 128, 64, lds + 57344, tid);
  asm volatile("s_waitcnt vmcnt(0)" ::: "memory");
  __builtin_amdgcn_s_barrier();

  // additive pass: acc += H·L2a + bias; same chunking
#pragma unroll
  for (int nh = 0; nh < 2; ++nh) {
#pragma unroll
    for (int mh = 0; mh < 2; ++mh) {
      f32x4 macc[4][2];
#pragma unroll
      for (int m = 0; m < 4; ++m)
#pragma unroll
        for (int j = 0; j < 2; ++j)
#pragma unroll
          for (int v = 0; v < 4; ++v) macc[m][j][v] = 0.f;
#pragma unroll
      for (int kc = 0; kc < 4; ++kc) {
        const u16* Hb = lds + (kc >> 1) * 16384;
        const u16* Lb = lds + 32768 + (kc >> 1) * 16384;
        int ks = kc & 1;
        bf16x8 lf[2];
#pragma unroll
        for (int j = 0; j < 2; ++j) {
          int q = wg_n * 64 + (nh * 2 + j) * 16 + lr;
          lf[j] = ld_frag(Lb + (q >> 7) * 8192, q & 127, ks, lane);
        }
#pragma unroll
        for (int mf = 0; mf < 4; ++mf) {
          int q = wg_m * 128 + (mh * 4 + mf) * 16 + lr;
          bf16x8 hf = ld_frag(Hb + (q >> 7) * 8192, q & 127, ks, lane);
          macc[mf][0] = __builtin_amdgcn_mfma_f32_16x16x32_bf16(hf, lf[0], macc[mf][0], 0, 0, 0);
          macc[mf][1] = __builtin_amdgcn_mfma_f32_16x16x32_bf16(hf, lf[1], macc[mf][1], 0, 0, 0);
        }
      }
#pragma unroll
      for (int mf = 0; mf < 4; ++mf)
#pragma unroll
        for (int j = 0; j < 2; ++j)
#pragma unroll
          for (int v = 0; v < 4; ++v)
            acc[mh * 4 + mf][nh * 2 + j][v] += macc[mf][j][v] + bs_[nh * 2 + j];
    }
  }

  // ---- store ----
#pragma unroll
  for (int mf = 0; mf < 8; ++mf)
#pragma unroll
    for (int nf = 0; nf < 4; ++nf)
#pragma unroll
      for (int v = 0; v < 4; ++v) {
        int rg = bm0 + wg_m * 128 + mf * 16 + (lane >> 4) * 4 + v;
        int cg = bn0 + wg_n * 64 + nf * 16 + lr;
        out[(size_t)rg * OUT_F + cg] = acc[mf][nf][v];
      }
}

// ---------------- launch ----------------

extern "C" void kernel_launch(void* const* d_in, const int* in_sizes, int n_in,
                              void* d_out, int out_size, void* d_ws, size_t ws_size,
                              hipStream_t stream) {
  const float* input = (const float*)d_in[0];
  const int*   zm    = (const int*)d_in[1];
  const float* cb    = (const float*)d_in[2];
  const float* l1    = (const float*)d_in[3];
  const float* l2    = (const float*)d_in[4];
  const float* gs    = (const float*)d_in[5];
  const float* gb    = (const float*)d_in[6];
  const float* scale = (const float*)d_in[7];
  const float* bias  = (const float*)d_in[8];
  float* out = (float*)d_out;

  const size_t OFF_A  = 0;                                        // 64 MiB
  const size_t OFF_W  = OFF_A + (size_t)NTOK * IN_F * 2;          // 32 MiB
  const size_t OFF_L1 = OFF_W + (size_t)OUT_F * IN_F * 2;         // 1 MiB
  const size_t OFF_L2 = OFF_L1 + (size_t)LRANK * IN_F * 2;        // 2 MiB
  const size_t OFF_H  = OFF_L2 + (size_t)2 * OUT_F * LRANK * 2;   // 2 MiB
  const size_t NEED   = OFF_H + (size_t)NTOK * LRANK * 2;
  if (ws_size < NEED) return;

  char* ws = (char*)d_ws;
  u16* A   = (u16*)(ws + OFF_A);
  u16* W   = (u16*)(ws + OFF_W);
  u16* L1b = (u16*)(ws + OFF_L1);
  u16* L2b = (u16*)(ws + OFF_L2);
  u16* H   = (u16*)(ws + OFF_H);

  cvt_bf16_kernel<<<(NTOK * IN_F / 4) / 256, 256, 0, stream>>>(input, A, NTOK * IN_F / 4);
  cvt_bf16_kernel<<<(LRANK * IN_F / 4) / 256, 256, 0, stream>>>(l1, L1b, LRANK * IN_F / 4);
  cvt_bf16_kernel<<<(2 * OUT_F * LRANK / 4) / 256, 256, 0, stream>>>(l2, L2b, 2 * OUT_F * LRANK / 4);
  dequant_kernel<<<(OUT_F * IN_F / 4) / 256, 256, 0, stream>>>(zm, cb, gs, gb, W);

  gemm_hid<<<NTOK / 128, 256, 0, stream>>>(A, L1b, H);

  gemm_main<<<(NTOK / 256) * (OUT_F / 256), 512, 0, stream>>>(A, W, H, L2b, scale, bias, out);
}

// Round 6
// 466.783 us; speedup vs baseline: 1.5047x; 1.5047x over previous
//
#include <hip/hip_runtime.h>
#include <hip/hip_bf16.h>

#define IN_F   4096
#define OUT_F  4096
#define NTOK   8192
#define LRANK  128

typedef unsigned short u16;
typedef __attribute__((ext_vector_type(8))) __bf16 bf16x8;
typedef __attribute__((ext_vector_type(4))) float f32x4;

__device__ __forceinline__ u16 f2bf(float f) {
  union { float f; unsigned u; } a; a.f = f;
  return (u16)((a.u + 0x7fffu + ((a.u >> 16) & 1u)) >> 16);
}

// async global->LDS, 16B per lane. LDS dest is wave-uniform base + lane*16.
__device__ __forceinline__ void async_ld16(const void* g, void* l) {
  __builtin_amdgcn_global_load_lds(
      (__attribute__((address_space(1))) void*)(unsigned long long)g,
      (__attribute__((address_space(3))) void*)(unsigned int)(unsigned long long)l,
      16, 0, 0);
}

// ---------------- prep kernels ----------------

__global__ void cvt_bf16_kernel(const float* __restrict__ src, u16* __restrict__ dst, int n4) {
  int i = blockIdx.x * blockDim.x + threadIdx.x;
  if (i >= n4) return;
  float4 v = ((const float4*)src)[i];
  ushort4 o;
  o.x = f2bf(v.x); o.y = f2bf(v.y); o.z = f2bf(v.z); o.w = f2bf(v.w);
  ((ushort4*)dst)[i] = o;
}

__global__ void dequant_kernel(const int* __restrict__ zm, const float* __restrict__ cb,
                               const float* __restrict__ gs, const float* __restrict__ gb,
                               u16* __restrict__ W) {
  int idx = blockIdx.x * blockDim.x + threadIdx.x;   // one thread per 4 weights
  if (idx >= OUT_F * IN_F / 4) return;
  int o = idx >> 10;
  int i = (idx & 1023) << 2;
  int row = ((o >> 6) << 6) + (i >> 6);
  const int* zp = zm + ((size_t)row << 12) + ((o & 63) << 6) + (i & 63);
  int4 z = *(const int4*)zp;
  const float* cr = cb + ((size_t)row << 8);
  int g = (o >> 3) * (IN_F / 8) + (i >> 3);
  float s = gs[g], b = gb[g];
  ushort4 w;
  w.x = f2bf(b + cr[z.x] * s);
  w.y = f2bf(b + cr[z.y] * s);
  w.z = f2bf(b + cr[z.z] * s);
  w.w = f2bf(b + cr[z.w] * s);
  *(ushort4*)(W + (size_t)idx * 4) = w;
}

// ---------------- hid GEMM (unchanged, correct) ----------------

__device__ __forceinline__ void stage_tile_128x32(const u16* __restrict__ g, int stride,
                                                  int row0, int col0,
                                                  u16* lbase, int wave, int lane) {
#pragma unroll
  for (int p = 0; p < 2; ++p) {
    int li_base = wave * 64 + p * 256;
    int li = li_base + lane;
    const u16* gaddr = g + (size_t)(row0 + (li >> 2)) * stride + col0 + ((li & 3) << 3);
    async_ld16(gaddr, lbase + li_base * 8);
  }
}

__global__ __launch_bounds__(256) void gemm_hid(const u16* __restrict__ A,
                                                const u16* __restrict__ L1,
                                                u16* __restrict__ H) {
  __shared__ __align__(16) u16 lds[2 * 128 * 32];
  u16* ldsA = lds;
  u16* ldsB = lds + 128 * 32;

  int tid = threadIdx.x;
  int wave = tid >> 6, lane = tid & 63;
  int bm0 = blockIdx.x * 128;
  int wr = (wave >> 1) * 64, wc = (wave & 1) * 64;
  int lrow = lane & 15, lk = (lane >> 4) * 8;

  f32x4 acc[4][4];
#pragma unroll
  for (int m = 0; m < 4; ++m)
#pragma unroll
    for (int n = 0; n < 4; ++n)
#pragma unroll
      for (int v = 0; v < 4; ++v) acc[m][n][v] = 0.f;

  for (int kt = 0; kt < IN_F / 32; ++kt) {
    int k0 = kt * 32;
    stage_tile_128x32(A, IN_F, bm0, k0, ldsA, wave, lane);
    stage_tile_128x32(L1, IN_F, 0, k0, ldsB, wave, lane);
    __syncthreads();
    bf16x8 af[4], bfr[4];
#pragma unroll
    for (int m = 0; m < 4; ++m)
      af[m] = *(const bf16x8*)&ldsA[(wr + m * 16 + lrow) * 32 + lk];
#pragma unroll
    for (int n = 0; n < 4; ++n)
      bfr[n] = *(const bf16x8*)&ldsB[(wc + n * 16 + lrow) * 32 + lk];
#pragma unroll
    for (int m = 0; m < 4; ++m)
#pragma unroll
      for (int n = 0; n < 4; ++n)
        acc[m][n] = __builtin_amdgcn_mfma_f32_16x16x32_bf16(af[m], bfr[n], acc[m][n], 0, 0, 0);
    __syncthreads();
  }

  int lrow4 = (lane >> 4) * 4;
#pragma unroll
  for (int m = 0; m < 4; ++m)
#pragma unroll
    for (int n = 0; n < 4; ++n)
#pragma unroll
      for (int v = 0; v < 4; ++v) {
        int rg = bm0 + wr + m * 16 + lrow4 + v;
        int cg = wc + n * 16 + lrow;
        H[(size_t)rg * LRANK + cg] = f2bf(acc[m][n][v]);
      }
}

// ---------------- main GEMM: 256x256 tile, BK=64, 8-phase schedule ----------------
// Ledger identical to the (correctness-verified) round-2 schedule.
// All staging/frag addressing precomputed to per-lane constants to keep
// arch-VGPR demand under the 128-reg partition (acc[8][4]=128 AGPRs).

#define MFMA_QUAD(mh, nh)                                                        \
  _Pragma("unroll") for (int mf = 0; mf < 4; ++mf)                               \
  _Pragma("unroll") for (int nf = 0; nf < 2; ++nf)                               \
  _Pragma("unroll") for (int ks = 0; ks < 2; ++ks)                               \
    acc[(mh)*4 + mf][(nh)*2 + nf] = __builtin_amdgcn_mfma_f32_16x16x32_bf16(     \
        af[mf][ks], bfr[nh][nf][ks], acc[(mh)*4 + mf][(nh)*2 + nf], 0, 0, 0);

#define PHASE_MID                                          \
  __builtin_amdgcn_s_barrier();                            \
  asm volatile("s_waitcnt lgkmcnt(0)" ::: "memory");       \
  __builtin_amdgcn_sched_barrier(0);                       \
  __builtin_amdgcn_s_setprio(1);

#define PHASE_END                                          \
  __builtin_amdgcn_s_setprio(0);                           \
  __builtin_amdgcn_s_barrier();

#define PHASE_END_VM                                       \
  __builtin_amdgcn_s_setprio(0);                           \
  asm volatile("s_waitcnt vmcnt(4)" ::: "memory");         \
  __builtin_amdgcn_s_barrier();

// LDS regions (bytes): buf b at b*65536; A halves +0,+16384; B halves +32768,+49152
#define LAB(b, h) ((char*)lds + (b) * 65536 + (h) * 16384)
#define LBB(b, h) ((char*)lds + (b) * 65536 + 32768 + (h) * 16384)

// stage one 128x64 half-tile: uniform base + precomputed per-lane offsets
#define STG_K(gbase, lreg) do {                               \
    async_ld16((gbase) + gK0, (lreg) + ldst0);                \
    async_ld16((gbase) + gK1, (lreg) + ldst0 + 8192); } while (0)
#define STG_L(gbase, lreg) do {                               \
    async_ld16((gbase) + gL0, (lreg) + ldst0);                \
    async_ld16((gbase) + gL1, (lreg) + ldst0 + 8192); } while (0)

// swizzled frag read: wave-uniform region ptr + compile-time row offset + lane const
#define LDF(p, byteoff, lb) (*(const bf16x8*)((p) + (byteoff) + (lb)))

__global__ __launch_bounds__(512)
__attribute__((amdgpu_waves_per_eu(2, 2)))
void gemm_main(const u16* __restrict__ A,
               const u16* __restrict__ W,
               const u16* __restrict__ H,
               const u16* __restrict__ L2,
               const float* __restrict__ scale,
               const float* __restrict__ bias,
               float* __restrict__ out) {
  __shared__ __align__(16) u16 lds[65536];   // 128 KiB

  const int tid = threadIdx.x;
  const int lane = tid & 63, wave = tid >> 6;
  const int wg_m = wave >> 2, wg_n = wave & 3;
  const int lr = lane & 15;

  // bijective XCD swizzle (nwg=512, 512%8==0)
  int bid = blockIdx.x;
  int swz = (bid & 7) * 64 + (bid >> 3);
  const int bn0 = (swz & 15) * 256;
  const int bm0 = (swz >> 4) * 256;

  // ---- per-lane staging constants (element offsets within a half-tile) ----
  // chunk c = tid + p*512; row = c>>3, slot = c&7; col = (slot ^ (row&7))*8.
  // p=1: row += 64 -> row&7 unchanged -> same swizzle, +64*stride elements.
  const int row_c = tid >> 3;
  const int xslot = ((tid & 7) ^ (row_c & 7)) << 3;
  const int gK0 = row_c * IN_F + xslot;          // stride IN_F streams (A, W)
  const int gK1 = gK0 + 64 * IN_F;
  const int gL0 = row_c * LRANK + xslot;         // stride LRANK streams (H, L2)
  const int gL1 = gL0 + 64 * LRANK;
  const int ldst0 = (tid & ~63) * 16;            // LDS dest byte (wave-uniform + HW lane*16)

  // ---- per-lane frag-read constants ----
  // byte = (r<<7) + [((ks<<2)|(lane>>4)) ^ (r&7)]<<4 with r = rbase16 + lr  (rbase16 % 16 == 0)
  const int lb0 = (lr << 7) | ((((lane >> 4)) ^ (lr & 7)) << 4);
  const int lb1 = (lr << 7) | (((4 | (lane >> 4)) ^ (lr & 7)) << 4);

  // uniform stream bases
  const u16* baseA0 = A + (size_t)bm0 * IN_F;
  const u16* baseA1 = A + (size_t)(bm0 + 128) * IN_F;
  const u16* baseW0 = W + (size_t)bn0 * IN_F;
  const u16* baseW1 = W + (size_t)(bn0 + 128) * IN_F;

  // wave-uniform frag-read region pointers
  const int b_row0 = (wg_n & 1) * 64;            // row base within B half
  const char* pA0 = LAB(0, wg_m);
  const char* pA1 = LAB(1, wg_m);
  const char* pB0 = LBB(0, wg_n >> 1) + b_row0 * 128;
  const char* pB1 = LBB(1, wg_n >> 1) + b_row0 * 128;

  f32x4 acc[8][4];
#pragma unroll
  for (int m = 0; m < 8; ++m)
#pragma unroll
    for (int n = 0; n < 4; ++n)
#pragma unroll
      for (int v = 0; v < 4; ++v) acc[m][n][v] = 0.f;

  // ---- prologue: kt0 -> buf0 (B0,B1,A0,A1), kt1.B -> buf1 ----
  STG_K(baseW0, LBB(0, 0));
  STG_K(baseW1, LBB(0, 1));
  STG_K(baseA0, LAB(0, 0));
  STG_K(baseA1, LAB(0, 1));
  STG_K(baseW0 + 64, LBB(1, 0));
  STG_K(baseW1 + 64, LBB(1, 1));
  asm volatile("s_waitcnt vmcnt(4)" ::: "memory");   // kt0 landed; kt1.B may fly
  __builtin_amdgcn_s_barrier();

  bf16x8 af[4][2];        // current A m-half (4 m-frags x 2 k-slices)
  bf16x8 bfr[2][2][2];    // both B n-halves kept ([nh][nf][ks])

  for (int u = 0; u < 32; ++u) {
    const int c1k = (2 * u + 1) * 64;
    const int n0  = 2 * u + 2, n1 = 2 * u + 3;
    const int n0k = (n0 > 63 ? 63 : n0) * 64;
    const int n1k = (n1 > 63 ? 63 : n1) * 64;

    // ---- P1: quad(0,0) on buf0 ----
#pragma unroll
    for (int mf = 0; mf < 4; ++mf) {
      af[mf][0] = LDF(pA0, mf * 2048, lb0);
      af[mf][1] = LDF(pA0, mf * 2048, lb1);
    }
#pragma unroll
    for (int nf = 0; nf < 2; ++nf) {
      bfr[0][nf][0] = LDF(pB0, nf * 2048, lb0);
      bfr[0][nf][1] = LDF(pB0, nf * 2048, lb1);
    }
    STG_K(baseA0 + c1k, LAB(1, 0));
    PHASE_MID; MFMA_QUAD(0, 0); PHASE_END;

    // ---- P2: quad(0,1) ----
#pragma unroll
    for (int nf = 0; nf < 2; ++nf) {
      bfr[1][nf][0] = LDF(pB0, 4096 + nf * 2048, lb0);
      bfr[1][nf][1] = LDF(pB0, 4096 + nf * 2048, lb1);
    }
    STG_K(baseA1 + c1k, LAB(1, 1));
    PHASE_MID; MFMA_QUAD(0, 1); PHASE_END;

    // ---- P3: quad(1,1) ----
#pragma unroll
    for (int mf = 0; mf < 4; ++mf) {
      af[mf][0] = LDF(pA0, 8192 + mf * 2048, lb0);
      af[mf][1] = LDF(pA0, 8192 + mf * 2048, lb1);
    }
    STG_K(baseW0 + n0k, LBB(0, 0));
    PHASE_MID; MFMA_QUAD(1, 1); PHASE_END;

    // ---- P4: quad(1,0) (all regs) ----
    STG_K(baseW1 + n0k, LBB(0, 1));
    PHASE_MID; MFMA_QUAD(1, 0); PHASE_END_VM;

    // ---- P5: quad(0,0) on buf1 ----
#pragma unroll
    for (int mf = 0; mf < 4; ++mf) {
      af[mf][0] = LDF(pA1, mf * 2048, lb0);
      af[mf][1] = LDF(pA1, mf * 2048, lb1);
    }
#pragma unroll
    for (int nf = 0; nf < 2; ++nf) {
      bfr[0][nf][0] = LDF(pB1, nf * 2048, lb0);
      bfr[0][nf][1] = LDF(pB1, nf * 2048, lb1);
    }
    STG_K(baseA0 + n0k, LAB(0, 0));
    PHASE_MID; MFMA_QUAD(0, 0); PHASE_END;

    // ---- P6: quad(0,1) ----
#pragma unroll
    for (int nf = 0; nf < 2; ++nf) {
      bfr[1][nf][0] = LDF(pB1, 4096 + nf * 2048, lb0);
      bfr[1][nf][1] = LDF(pB1, 4096 + nf * 2048, lb1);
    }
    STG_K(baseA1 + n0k, LAB(0, 1));
    PHASE_MID; MFMA_QUAD(0, 1); PHASE_END;

    // ---- P7: quad(1,1) ----
#pragma unroll
    for (int mf = 0; mf < 4; ++mf) {
      af[mf][0] = LDF(pA1, 8192 + mf * 2048, lb0);
      af[mf][1] = LDF(pA1, 8192 + mf * 2048, lb1);
    }
    STG_K(baseW0 + n1k, LBB(1, 0));
    PHASE_MID; MFMA_QUAD(1, 1); PHASE_END;

    // ---- P8: quad(1,0) (all regs) ----
    STG_K(baseW1 + n1k, LBB(1, 1));
    PHASE_MID; MFMA_QUAD(1, 0); PHASE_END_VM;
  }

  // ---- drain outstanding stages before LDS reuse ----
  asm volatile("s_waitcnt vmcnt(0)" ::: "memory");
  __builtin_amdgcn_s_barrier();

  // ---- fused low-rank epilogue ----
  float scl[4], bs_[4];
#pragma unroll
  for (int nf = 0; nf < 4; ++nf) {
    int cg = bn0 + wg_n * 64 + nf * 16 + lr;
    scl[nf] = scale[cg];
    bs_[nf] = bias[cg];
  }

  // epilogue LDS (bytes): H(s,h) = s*32768 + h*16384 ; L2(s,h) = 65536 + s*32768 + h*16384
  // s = K-col subtile (0: k 0-63, 1: k 64-127); h = row half.
  {
    const u16* baseH0 = H + (size_t)bm0 * LRANK;
    const u16* baseH1 = H + (size_t)(bm0 + 128) * LRANK;
    const u16* baseL0 = L2 + (size_t)bn0 * LRANK;
    const u16* baseL1 = L2 + (size_t)(bn0 + 128) * LRANK;
    STG_L(baseH0,      (char*)lds + 0);
    STG_L(baseH1,      (char*)lds + 16384);
    STG_L(baseH0 + 64, (char*)lds + 32768);
    STG_L(baseH1 + 64, (char*)lds + 49152);
    STG_L(baseL0,      (char*)lds + 65536);
    STG_L(baseL1,      (char*)lds + 81920);
    STG_L(baseL0 + 64, (char*)lds + 98304);
    STG_L(baseL1 + 64, (char*)lds + 114688);
  }
  asm volatile("s_waitcnt vmcnt(0)" ::: "memory");
  __builtin_amdgcn_s_barrier();

  // wave-uniform epilogue region pointers (kc-half 0); +32768 bytes for kc-half 1
  const char* pH = (char*)lds + wg_m * 16384;
  const char* pL = (char*)lds + 65536 + (wg_n >> 1) * 16384 + (wg_n & 1) * 8192;

  // multiplicative pass: acc *= (H·L2m + scale); macc chunked [2][2]
#pragma unroll
  for (int nh = 0; nh < 2; ++nh)
#pragma unroll
    for (int mq = 0; mq < 4; ++mq) {
      f32x4 macc[2][2];
#pragma unroll
      for (int m = 0; m < 2; ++m)
#pragma unroll
        for (int j = 0; j < 2; ++j)
#pragma unroll
          for (int v = 0; v < 4; ++v) macc[m][j][v] = 0.f;
#pragma unroll
      for (int kc = 0; kc < 4; ++kc) {
        const int sb = (kc >> 1) * 32768;
        const int lb = (kc & 1) ? lb1 : lb0;
        bf16x8 lf0 = LDF(pL + sb, (nh * 2 + 0) * 2048, lb);
        bf16x8 lf1 = LDF(pL + sb, (nh * 2 + 1) * 2048, lb);
#pragma unroll
        for (int mf = 0; mf < 2; ++mf) {
          bf16x8 hf = LDF(pH + sb, (mq * 2 + mf) * 2048, lb);
          macc[mf][0] = __builtin_amdgcn_mfma_f32_16x16x32_bf16(hf, lf0, macc[mf][0], 0, 0, 0);
          macc[mf][1] = __builtin_amdgcn_mfma_f32_16x16x32_bf16(hf, lf1, macc[mf][1], 0, 0, 0);
        }
      }
#pragma unroll
      for (int mf = 0; mf < 2; ++mf)
#pragma unroll
        for (int j = 0; j < 2; ++j)
#pragma unroll
          for (int v = 0; v < 4; ++v)
            acc[mq * 2 + mf][nh * 2 + j][v] *= (macc[mf][j][v] + scl[nh * 2 + j]);
    }

  // restage L2 additive rows
  __builtin_amdgcn_s_barrier();
  {
    const u16* baseL0 = L2 + (size_t)(OUT_F + bn0) * LRANK;
    const u16* baseL1 = L2 + (size_t)(OUT_F + bn0 + 128) * LRANK;
    STG_L(baseL0,      (char*)lds + 65536);
    STG_L(baseL1,      (char*)lds + 81920);
    STG_L(baseL0 + 64, (char*)lds + 98304);
    STG_L(baseL1 + 64, (char*)lds + 114688);
  }
  asm volatile("s_waitcnt vmcnt(0)" ::: "memory");
  __builtin_amdgcn_s_barrier();

  // additive pass: acc += H·L2a + bias; same chunking
#pragma unroll
  for (int nh = 0; nh < 2; ++nh)
#pragma unroll
    for (int mq = 0; mq < 4; ++mq) {
      f32x4 macc[2][2];
#pragma unroll
      for (int m = 0; m < 2; ++m)
#pragma unroll
        for (int j = 0; j < 2; ++j)
#pragma unroll
          for (int v = 0; v < 4; ++v) macc[m][j][v] = 0.f;
#pragma unroll
      for (int kc = 0; kc < 4; ++kc) {
        const int sb = (kc >> 1) * 32768;
        const int lb = (kc & 1) ? lb1 : lb0;
        bf16x8 lf0 = LDF(pL + sb, (nh * 2 + 0) * 2048, lb);
        bf16x8 lf1 = LDF(pL + sb, (nh * 2 + 1) * 2048, lb);
#pragma unroll
        for (int mf = 0; mf < 2; ++mf) {
          bf16x8 hf = LDF(pH + sb, (mq * 2 + mf) * 2048, lb);
          macc[mf][0] = __builtin_amdgcn_mfma_f32_16x16x32_bf16(hf, lf0, macc[mf][0], 0, 0, 0);
          macc[mf][1] = __builtin_amdgcn_mfma_f32_16x16x32_bf16(hf, lf1, macc[mf][1], 0, 0, 0);
        }
      }
#pragma unroll
      for (int mf = 0; mf < 2; ++mf)
#pragma unroll
        for (int j = 0; j < 2; ++j)
#pragma unroll
          for (int v = 0; v < 4; ++v)
            acc[mq * 2 + mf][nh * 2 + j][v] += macc[mf][j][v] + bs_[nh * 2 + j];
    }

  // ---- store ----
#pragma unroll
  for (int mf = 0; mf < 8; ++mf)
#pragma unroll
    for (int nf = 0; nf < 4; ++nf)
#pragma unroll
      for (int v = 0; v < 4; ++v) {
        int rg = bm0 + wg_m * 128 + mf * 16 + (lane >> 4) * 4 + v;
        int cg = bn0 + wg_n * 64 + nf * 16 + lr;
        out[(size_t)rg * OUT_F + cg] = acc[mf][nf][v];
      }
}

// ---------------- launch ----------------

extern "C" void kernel_launch(void* const* d_in, const int* in_sizes, int n_in,
                              void* d_out, int out_size, void* d_ws, size_t ws_size,
                              hipStream_t stream) {
  const float* input = (const float*)d_in[0];
  const int*   zm    = (const int*)d_in[1];
  const float* cb    = (const float*)d_in[2];
  const float* l1    = (const float*)d_in[3];
  const float* l2    = (const float*)d_in[4];
  const float* gs    = (const float*)d_in[5];
  const float* gb    = (const float*)d_in[6];
  const float* scale = (const float*)d_in[7];
  const float* bias  = (const float*)d_in[8];
  float* out = (float*)d_out;

  const size_t OFF_A  = 0;                                        // 64 MiB
  const size_t OFF_W  = OFF_A + (size_t)NTOK * IN_F * 2;          // 32 MiB
  const size_t OFF_L1 = OFF_W + (size_t)OUT_F * IN_F * 2;         // 1 MiB
  const size_t OFF_L2 = OFF_L1 + (size_t)LRANK * IN_F * 2;        // 2 MiB
  const size_t OFF_H  = OFF_L2 + (size_t)2 * OUT_F * LRANK * 2;   // 2 MiB
  const size_t NEED   = OFF_H + (size_t)NTOK * LRANK * 2;
  if (ws_size < NEED) return;

  char* ws = (char*)d_ws;
  u16* A   = (u16*)(ws + OFF_A);
  u16* W   = (u16*)(ws + OFF_W);
  u16* L1b = (u16*)(ws + OFF_L1);
  u16* L2b = (u16*)(ws + OFF_L2);
  u16* H   = (u16*)(ws + OFF_H);

  cvt_bf16_kernel<<<(NTOK * IN_F / 4) / 256, 256, 0, stream>>>(input, A, NTOK * IN_F / 4);
  cvt_bf16_kernel<<<(LRANK * IN_F / 4) / 256, 256, 0, stream>>>(l1, L1b, LRANK * IN_F / 4);
  cvt_bf16_kernel<<<(2 * OUT_F * LRANK / 4) / 256, 256, 0, stream>>>(l2, L2b, 2 * OUT_F * LRANK / 4);
  dequant_kernel<<<(OUT_F * IN_F / 4) / 256, 256, 0, stream>>>(zm, cb, gs, gb, W);

  gemm_hid<<<NTOK / 128, 256, 0, stream>>>(A, L1b, H);

  gemm_main<<<(NTOK / 256) * (OUT_F / 256), 512, 0, stream>>>(A, W, H, L2b, scale, bias, out);
}

// Round 7
// 427.138 us; speedup vs baseline: 1.6444x; 1.0928x over previous
//
#include <hip/hip_runtime.h>
#include <hip/hip_bf16.h>

#define IN_F   4096
#define OUT_F  4096
#define NTOK   8192
#define LRANK  128

typedef unsigned short u16;
typedef unsigned int u32;
typedef __attribute__((ext_vector_type(8))) __bf16 bf16x8;
typedef __attribute__((ext_vector_type(4))) float f32x4;

__device__ __forceinline__ u16 f2bf(float f) {
  union { float f; unsigned u; } a; a.f = f;
  return (u16)((a.u + 0x7fffu + ((a.u >> 16) & 1u)) >> 16);
}
__device__ __forceinline__ float bf2f(u16 b) {
  union { unsigned u; float f; } a; a.u = (u32)b << 16;
  return a.f;
}

// async global->LDS, 16B per lane. LDS dest is wave-uniform base + lane*16.
__device__ __forceinline__ void async_ld16(const void* g, void* l) {
  __builtin_amdgcn_global_load_lds(
      (__attribute__((address_space(1))) void*)(unsigned long long)g,
      (__attribute__((address_space(3))) void*)(unsigned int)(unsigned long long)l,
      16, 0, 0);
}

// ---------------- prep kernels ----------------

__global__ void cvt_bf16_kernel(const float* __restrict__ src, u16* __restrict__ dst, int n4) {
  int i = blockIdx.x * blockDim.x + threadIdx.x;
  if (i >= n4) return;
  float4 v = ((const float4*)src)[i];
  ushort4 o;
  o.x = f2bf(v.x); o.y = f2bf(v.y); o.z = f2bf(v.z); o.w = f2bf(v.w);
  ((ushort4*)dst)[i] = o;
}

__global__ void dequant_kernel(const int* __restrict__ zm, const float* __restrict__ cb,
                               const float* __restrict__ gs, const float* __restrict__ gb,
                               u16* __restrict__ W) {
  int idx = blockIdx.x * blockDim.x + threadIdx.x;   // one thread per 4 weights
  if (idx >= OUT_F * IN_F / 4) return;
  int o = idx >> 10;
  int i = (idx & 1023) << 2;
  int row = ((o >> 6) << 6) + (i >> 6);
  const int* zp = zm + ((size_t)row << 12) + ((o & 63) << 6) + (i & 63);
  int4 z = *(const int4*)zp;
  const float* cr = cb + ((size_t)row << 8);
  int g = (o >> 3) * (IN_F / 8) + (i >> 3);
  float s = gs[g], b = gb[g];
  ushort4 w;
  w.x = f2bf(b + cr[z.x] * s);
  w.y = f2bf(b + cr[z.y] * s);
  w.z = f2bf(b + cr[z.z] * s);
  w.w = f2bf(b + cr[z.w] * s);
  *(ushort4*)(W + (size_t)idx * 4) = w;
}

// ---------------- hid GEMM (unchanged, correct) ----------------

__device__ __forceinline__ void stage_tile_128x32(const u16* __restrict__ g, int stride,
                                                  int row0, int col0,
                                                  u16* lbase, int wave, int lane) {
#pragma unroll
  for (int p = 0; p < 2; ++p) {
    int li_base = wave * 64 + p * 256;
    int li = li_base + lane;
    const u16* gaddr = g + (size_t)(row0 + (li >> 2)) * stride + col0 + ((li & 3) << 3);
    async_ld16(gaddr, lbase + li_base * 8);
  }
}

__global__ __launch_bounds__(256) void gemm_hid(const u16* __restrict__ A,
                                                const u16* __restrict__ L1,
                                                u16* __restrict__ H) {
  __shared__ __align__(16) u16 lds[2 * 128 * 32];
  u16* ldsA = lds;
  u16* ldsB = lds + 128 * 32;

  int tid = threadIdx.x;
  int wave = tid >> 6, lane = tid & 63;
  int bm0 = blockIdx.x * 128;
  int wr = (wave >> 1) * 64, wc = (wave & 1) * 64;
  int lrow = lane & 15, lk = (lane >> 4) * 8;

  f32x4 acc[4][4];
#pragma unroll
  for (int m = 0; m < 4; ++m)
#pragma unroll
    for (int n = 0; n < 4; ++n)
#pragma unroll
      for (int v = 0; v < 4; ++v) acc[m][n][v] = 0.f;

  for (int kt = 0; kt < IN_F / 32; ++kt) {
    int k0 = kt * 32;
    stage_tile_128x32(A, IN_F, bm0, k0, ldsA, wave, lane);
    stage_tile_128x32(L1, IN_F, 0, k0, ldsB, wave, lane);
    __syncthreads();
    bf16x8 af[4], bfr[4];
#pragma unroll
    for (int m = 0; m < 4; ++m)
      af[m] = *(const bf16x8*)&ldsA[(wr + m * 16 + lrow) * 32 + lk];
#pragma unroll
    for (int n = 0; n < 4; ++n)
      bfr[n] = *(const bf16x8*)&ldsB[(wc + n * 16 + lrow) * 32 + lk];
#pragma unroll
    for (int m = 0; m < 4; ++m)
#pragma unroll
      for (int n = 0; n < 4; ++n)
        acc[m][n] = __builtin_amdgcn_mfma_f32_16x16x32_bf16(af[m], bfr[n], acc[m][n], 0, 0, 0);
    __syncthreads();
  }

  int lrow4 = (lane >> 4) * 4;
#pragma unroll
  for (int m = 0; m < 4; ++m)
#pragma unroll
    for (int n = 0; n < 4; ++n)
#pragma unroll
      for (int v = 0; v < 4; ++v) {
        int rg = bm0 + wr + m * 16 + lrow4 + v;
        int cg = wc + n * 16 + lrow;
        H[(size_t)rg * LRANK + cg] = f2bf(acc[m][n][v]);
      }
}

// ---------------- main GEMM: 256x256 tile, BK=64, 8-phase schedule ----------------
// Pure GEMM (low-rank epilogue unfused -> lr_apply). Writes baseline as packed
// bf16 in NATIVE per-thread layout: uint2 at ((bid*8+wave)*32 + mf*4+nf)*64+lane.

#define MFMA_QUAD(mh, nh)                                                        \
  _Pragma("unroll") for (int mf = 0; mf < 4; ++mf)                               \
  _Pragma("unroll") for (int nf = 0; nf < 2; ++nf)                               \
  _Pragma("unroll") for (int ks = 0; ks < 2; ++ks)                               \
    acc[(mh)*4 + mf][(nh)*2 + nf] = __builtin_amdgcn_mfma_f32_16x16x32_bf16(     \
        af[mf][ks], bfr[nh][nf][ks], acc[(mh)*4 + mf][(nh)*2 + nf], 0, 0, 0);

#define PHASE_MID                                          \
  __builtin_amdgcn_s_barrier();                            \
  asm volatile("s_waitcnt lgkmcnt(0)" ::: "memory");       \
  __builtin_amdgcn_sched_barrier(0);                       \
  __builtin_amdgcn_s_setprio(1);

#define PHASE_END                                          \
  __builtin_amdgcn_s_setprio(0);                           \
  __builtin_amdgcn_s_barrier();

#define PHASE_END_VM                                       \
  __builtin_amdgcn_s_setprio(0);                           \
  asm volatile("s_waitcnt vmcnt(4)" ::: "memory");         \
  __builtin_amdgcn_s_barrier();

#define PHASE_END_VM0                                      \
  __builtin_amdgcn_s_setprio(0);                           \
  asm volatile("s_waitcnt vmcnt(0)" ::: "memory");         \
  __builtin_amdgcn_s_barrier();

// LDS regions (bytes): buf b at b*65536; A halves +0,+16384; B halves +32768,+49152
#define LAB(b, h) ((char*)lds + (b) * 65536 + (h) * 16384)
#define LBB(b, h) ((char*)lds + (b) * 65536 + 32768 + (h) * 16384)

#define STG_K(gbase, lreg) do {                               \
    async_ld16((gbase) + gK0, (lreg) + ldst0);                \
    async_ld16((gbase) + gK1, (lreg) + ldst0 + 8192); } while (0)
#define STG_L(gbase, lreg) do {                               \
    async_ld16((gbase) + gL0, (lreg) + ldst0);                \
    async_ld16((gbase) + gL1, (lreg) + ldst0 + 8192); } while (0)

#define LDF(p, byteoff, lb) (*(const bf16x8*)((p) + (byteoff) + (lb)))

__global__ __launch_bounds__(512)
__attribute__((amdgpu_waves_per_eu(2, 2)))
void gemm_main(const u16* __restrict__ A,
               const u16* __restrict__ W,
               uint2* __restrict__ Bl) {
  __shared__ __align__(16) u16 lds[65536];   // 128 KiB

  const int tid = threadIdx.x;
  const int lane = tid & 63, wave = tid >> 6;
  const int wg_m = wave >> 2;
  const int lr = lane & 15;

  // bijective XCD swizzle (nwg=512, 512%8==0)
  int bid = blockIdx.x;
  int swz = (bid & 7) * 64 + (bid >> 3);
  const int bn0 = (swz & 15) * 256;
  const int bm0 = (swz >> 4) * 256;

  // per-lane staging constants
  const int row_c = tid >> 3;
  const int xslot = ((tid & 7) ^ (row_c & 7)) << 3;
  const int gK0 = row_c * IN_F + xslot;
  const int gK1 = gK0 + 64 * IN_F;
  const int ldst0 = (tid & ~63) * 16;

  // per-lane frag-read constants
  const int lb0 = (lr << 7) | ((((lane >> 4)) ^ (lr & 7)) << 4);
  const int lb1 = (lr << 7) | (((4 | (lane >> 4)) ^ (lr & 7)) << 4);

  const u16* baseA0 = A + (size_t)bm0 * IN_F;
  const u16* baseA1 = A + (size_t)(bm0 + 128) * IN_F;
  const u16* baseW0 = W + (size_t)bn0 * IN_F;
  const u16* baseW1 = W + (size_t)(bn0 + 128) * IN_F;

  const int wg_n = wave & 3;
  const int b_row0 = (wg_n & 1) * 64;
  const char* pA0 = LAB(0, wg_m);
  const char* pA1 = LAB(1, wg_m);
  const char* pB0 = LBB(0, wg_n >> 1) + b_row0 * 128;
  const char* pB1 = LBB(1, wg_n >> 1) + b_row0 * 128;

  f32x4 acc[8][4];
#pragma unroll
  for (int m = 0; m < 8; ++m)
#pragma unroll
    for (int n = 0; n < 4; ++n)
#pragma unroll
      for (int v = 0; v < 4; ++v) acc[m][n][v] = 0.f;

  // ---- prologue: kt0 -> buf0 (B0,B1,A0,A1), kt1.B -> buf1 ----
  STG_K(baseW0, LBB(0, 0));
  STG_K(baseW1, LBB(0, 1));
  STG_K(baseA0, LAB(0, 0));
  STG_K(baseA1, LAB(0, 1));
  STG_K(baseW0 + 64, LBB(1, 0));
  STG_K(baseW1 + 64, LBB(1, 1));
  asm volatile("s_waitcnt vmcnt(4)" ::: "memory");
  __builtin_amdgcn_s_barrier();

  bf16x8 af[4][2];
  bf16x8 bfr[2][2][2];

  for (int u = 0; u < 31; ++u) {
    const int c1k = (2 * u + 1) * 64;
    const int n0k = (2 * u + 2) * 64;
    const int n1k = (2 * u + 3) * 64;

    // ---- P1: quad(0,0) on buf0 ----
#pragma unroll
    for (int mf = 0; mf < 4; ++mf) {
      af[mf][0] = LDF(pA0, mf * 2048, lb0);
      af[mf][1] = LDF(pA0, mf * 2048, lb1);
    }
#pragma unroll
    for (int nf = 0; nf < 2; ++nf) {
      bfr[0][nf][0] = LDF(pB0, nf * 2048, lb0);
      bfr[0][nf][1] = LDF(pB0, nf * 2048, lb1);
    }
    STG_K(baseA0 + c1k, LAB(1, 0));
    PHASE_MID; MFMA_QUAD(0, 0); PHASE_END;

    // ---- P2: quad(0,1) ----
#pragma unroll
    for (int nf = 0; nf < 2; ++nf) {
      bfr[1][nf][0] = LDF(pB0, 4096 + nf * 2048, lb0);
      bfr[1][nf][1] = LDF(pB0, 4096 + nf * 2048, lb1);
    }
    STG_K(baseA1 + c1k, LAB(1, 1));
    PHASE_MID; MFMA_QUAD(0, 1); PHASE_END;

    // ---- P3: quad(1,1) ----
#pragma unroll
    for (int mf = 0; mf < 4; ++mf) {
      af[mf][0] = LDF(pA0, 8192 + mf * 2048, lb0);
      af[mf][1] = LDF(pA0, 8192 + mf * 2048, lb1);
    }
    STG_K(baseW0 + n0k, LBB(0, 0));
    PHASE_MID; MFMA_QUAD(1, 1); PHASE_END;

    // ---- P4: quad(1,0) ----
    STG_K(baseW1 + n0k, LBB(0, 1));
    PHASE_MID; MFMA_QUAD(1, 0); PHASE_END_VM;

    // ---- P5: quad(0,0) on buf1 ----
#pragma unroll
    for (int mf = 0; mf < 4; ++mf) {
      af[mf][0] = LDF(pA1, mf * 2048, lb0);
      af[mf][1] = LDF(pA1, mf * 2048, lb1);
    }
#pragma unroll
    for (int nf = 0; nf < 2; ++nf) {
      bfr[0][nf][0] = LDF(pB1, nf * 2048, lb0);
      bfr[0][nf][1] = LDF(pB1, nf * 2048, lb1);
    }
    STG_K(baseA0 + n0k, LAB(0, 0));
    PHASE_MID; MFMA_QUAD(0, 0); PHASE_END;

    // ---- P6: quad(0,1) ----
#pragma unroll
    for (int nf = 0; nf < 2; ++nf) {
      bfr[1][nf][0] = LDF(pB1, 4096 + nf * 2048, lb0);
      bfr[1][nf][1] = LDF(pB1, 4096 + nf * 2048, lb1);
    }
    STG_K(baseA1 + n0k, LAB(0, 1));
    PHASE_MID; MFMA_QUAD(0, 1); PHASE_END;

    // ---- P7: quad(1,1) ----
#pragma unroll
    for (int mf = 0; mf < 4; ++mf) {
      af[mf][0] = LDF(pA1, 8192 + mf * 2048, lb0);
      af[mf][1] = LDF(pA1, 8192 + mf * 2048, lb1);
    }
    STG_K(baseW0 + n1k, LBB(1, 0));
    PHASE_MID; MFMA_QUAD(1, 1); PHASE_END;

    // ---- P8: quad(1,0) ----
    STG_K(baseW1 + n1k, LBB(1, 1));
    PHASE_MID; MFMA_QUAD(1, 0); PHASE_END_VM;
  }

  // ---- peeled tail (u=31): only buf1.A (kt63) staged; no next-tile loads ----
  {
    const int c1k = 63 * 64;

    // P1
#pragma unroll
    for (int mf = 0; mf < 4; ++mf) {
      af[mf][0] = LDF(pA0, mf * 2048, lb0);
      af[mf][1] = LDF(pA0, mf * 2048, lb1);
    }
#pragma unroll
    for (int nf = 0; nf < 2; ++nf) {
      bfr[0][nf][0] = LDF(pB0, nf * 2048, lb0);
      bfr[0][nf][1] = LDF(pB0, nf * 2048, lb1);
    }
    STG_K(baseA0 + c1k, LAB(1, 0));
    PHASE_MID; MFMA_QUAD(0, 0); PHASE_END;

    // P2
#pragma unroll
    for (int nf = 0; nf < 2; ++nf) {
      bfr[1][nf][0] = LDF(pB0, 4096 + nf * 2048, lb0);
      bfr[1][nf][1] = LDF(pB0, 4096 + nf * 2048, lb1);
    }
    STG_K(baseA1 + c1k, LAB(1, 1));
    PHASE_MID; MFMA_QUAD(0, 1); PHASE_END;

    // P3
#pragma unroll
    for (int mf = 0; mf < 4; ++mf) {
      af[mf][0] = LDF(pA0, 8192 + mf * 2048, lb0);
      af[mf][1] = LDF(pA0, 8192 + mf * 2048, lb1);
    }
    PHASE_MID; MFMA_QUAD(1, 1); PHASE_END;

    // P4: only 4 loads outstanding -> must drain fully before buf1.A reads
    PHASE_MID; MFMA_QUAD(1, 0); PHASE_END_VM0;

    // P5
#pragma unroll
    for (int mf = 0; mf < 4; ++mf) {
      af[mf][0] = LDF(pA1, mf * 2048, lb0);
      af[mf][1] = LDF(pA1, mf * 2048, lb1);
    }
#pragma unroll
    for (int nf = 0; nf < 2; ++nf) {
      bfr[0][nf][0] = LDF(pB1, nf * 2048, lb0);
      bfr[0][nf][1] = LDF(pB1, nf * 2048, lb1);
    }
    PHASE_MID; MFMA_QUAD(0, 0); PHASE_END;

    // P6
#pragma unroll
    for (int nf = 0; nf < 2; ++nf) {
      bfr[1][nf][0] = LDF(pB1, 4096 + nf * 2048, lb0);
      bfr[1][nf][1] = LDF(pB1, 4096 + nf * 2048, lb1);
    }
    PHASE_MID; MFMA_QUAD(0, 1); PHASE_END;

    // P7
#pragma unroll
    for (int mf = 0; mf < 4; ++mf) {
      af[mf][0] = LDF(pA1, 8192 + mf * 2048, lb0);
      af[mf][1] = LDF(pA1, 8192 + mf * 2048, lb1);
    }
    PHASE_MID; MFMA_QUAD(1, 1); PHASE_END;

    // P8
    PHASE_MID; MFMA_QUAD(1, 0); PHASE_END;
  }

  // ---- store baseline: packed bf16, native per-thread layout ----
  const size_t tbase = ((size_t)bid * 8 + wave) * 32;
#pragma unroll
  for (int mf = 0; mf < 8; ++mf)
#pragma unroll
    for (int nf = 0; nf < 4; ++nf) {
      f32x4 a = acc[mf][nf];
      uint2 pk;
      pk.x = (u32)f2bf(a[0]) | ((u32)f2bf(a[1]) << 16);
      pk.y = (u32)f2bf(a[2]) | ((u32)f2bf(a[3]) << 16);
      Bl[(tbase + mf * 4 + nf) * 64 + lane] = pk;
    }
}

// ---------------- lr_apply: out = (H·L2a + bias) + (H·L2m + scale) * baseline ----------------
// Same geometry/swizzle as gemm_main; reads baseline in native layout.

__global__ __launch_bounds__(512)
void lr_apply(const uint2* __restrict__ Bl,
              const u16* __restrict__ H,
              const u16* __restrict__ L2,
              const float* __restrict__ scale,
              const float* __restrict__ bias,
              float* __restrict__ out) {
  __shared__ __align__(16) u16 lds[65536];   // 128 KiB

  const int tid = threadIdx.x;
  const int lane = tid & 63, wave = tid >> 6;
  const int wg_m = wave >> 2, wg_n = wave & 3;
  const int lr = lane & 15;

  int bid = blockIdx.x;
  int swz = (bid & 7) * 64 + (bid >> 3);
  const int bn0 = (swz & 15) * 256;
  const int bm0 = (swz >> 4) * 256;

  const int row_c = tid >> 3;
  const int xslot = ((tid & 7) ^ (row_c & 7)) << 3;
  const int gL0 = row_c * LRANK + xslot;
  const int gL1 = gL0 + 64 * LRANK;
  const int ldst0 = (tid & ~63) * 16;

  const int lb0 = (lr << 7) | ((((lane >> 4)) ^ (lr & 7)) << 4);
  const int lb1 = (lr << 7) | (((4 | (lane >> 4)) ^ (lr & 7)) << 4);

  float scl[4], bs_[4];
#pragma unroll
  for (int nf = 0; nf < 4; ++nf) {
    int cg = bn0 + wg_n * 64 + nf * 16 + lr;
    scl[nf] = scale[cg];
    bs_[nf] = bias[cg];
  }

  // stage H (4 halves) + L2m (4 halves):
  // H(s,h) = s*32768 + h*16384 ; L2(s,h) = 65536 + s*32768 + h*16384
  {
    const u16* baseH0 = H + (size_t)bm0 * LRANK;
    const u16* baseH1 = H + (size_t)(bm0 + 128) * LRANK;
    const u16* baseL0 = L2 + (size_t)bn0 * LRANK;
    const u16* baseL1 = L2 + (size_t)(bn0 + 128) * LRANK;
    STG_L(baseH0,      (char*)lds + 0);
    STG_L(baseH1,      (char*)lds + 16384);
    STG_L(baseH0 + 64, (char*)lds + 32768);
    STG_L(baseH1 + 64, (char*)lds + 49152);
    STG_L(baseL0,      (char*)lds + 65536);
    STG_L(baseL1,      (char*)lds + 81920);
    STG_L(baseL0 + 64, (char*)lds + 98304);
    STG_L(baseL1 + 64, (char*)lds + 114688);
  }
  __syncthreads();

  const char* pH = (char*)lds + wg_m * 16384;
  const char* pL = (char*)lds + 65536 + (wg_n >> 1) * 16384 + (wg_n & 1) * 8192;

  // full multiplicative accumulator
  f32x4 maccM[8][4];
#pragma unroll
  for (int m = 0; m < 8; ++m)
#pragma unroll
    for (int n = 0; n < 4; ++n)
#pragma unroll
      for (int v = 0; v < 4; ++v) maccM[m][n][v] = 0.f;

#pragma unroll
  for (int kc = 0; kc < 4; ++kc) {
    const int sb = (kc >> 1) * 32768;
    const int lb = (kc & 1) ? lb1 : lb0;
    bf16x8 lf[4];
#pragma unroll
    for (int nf = 0; nf < 4; ++nf)
      lf[nf] = LDF(pL + sb, nf * 2048, lb);
#pragma unroll
    for (int mf = 0; mf < 8; ++mf) {
      bf16x8 hf = LDF(pH + sb, mf * 2048, lb);
#pragma unroll
      for (int nf = 0; nf < 4; ++nf)
        maccM[mf][nf] = __builtin_amdgcn_mfma_f32_16x16x32_bf16(hf, lf[nf], maccM[mf][nf], 0, 0, 0);
    }
  }

  // restage L2 additive rows over the L2m region
  __syncthreads();
  {
    const u16* baseL0 = L2 + (size_t)(OUT_F + bn0) * LRANK;
    const u16* baseL1 = L2 + (size_t)(OUT_F + bn0 + 128) * LRANK;
    STG_L(baseL0,      (char*)lds + 65536);
    STG_L(baseL1,      (char*)lds + 81920);
    STG_L(baseL0 + 64, (char*)lds + 98304);
    STG_L(baseL1 + 64, (char*)lds + 114688);
  }
  __syncthreads();

  // additive pass chunked by m-quarter, immediate apply + store
  const size_t tbase = ((size_t)bid * 8 + wave) * 32;
#pragma unroll
  for (int mq = 0; mq < 4; ++mq) {
    f32x4 maccA[2][4];
#pragma unroll
    for (int m = 0; m < 2; ++m)
#pragma unroll
      for (int n = 0; n < 4; ++n)
#pragma unroll
        for (int v = 0; v < 4; ++v) maccA[m][n][v] = 0.f;

#pragma unroll
    for (int kc = 0; kc < 4; ++kc) {
      const int sb = (kc >> 1) * 32768;
      const int lb = (kc & 1) ? lb1 : lb0;
      bf16x8 lf[4];
#pragma unroll
      for (int nf = 0; nf < 4; ++nf)
        lf[nf] = LDF(pL + sb, nf * 2048, lb);
#pragma unroll
      for (int mf = 0; mf < 2; ++mf) {
        bf16x8 hf = LDF(pH + sb, (mq * 2 + mf) * 2048, lb);
#pragma unroll
        for (int nf = 0; nf < 4; ++nf)
          maccA[mf][nf] = __builtin_amdgcn_mfma_f32_16x16x32_bf16(hf, lf[nf], maccA[mf][nf], 0, 0, 0);
      }
    }

#pragma unroll
    for (int mf = 0; mf < 2; ++mf)
#pragma unroll
      for (int nf = 0; nf < 4; ++nf) {
        int m8 = mq * 2 + mf;
        uint2 pk = Bl[(tbase + m8 * 4 + nf) * 64 + lane];
        float b0 = bf2f((u16)(pk.x & 0xffff));
        float b1 = bf2f((u16)(pk.x >> 16));
        float b2 = bf2f((u16)(pk.y & 0xffff));
        float b3 = bf2f((u16)(pk.y >> 16));
        int rg = bm0 + wg_m * 128 + m8 * 16 + (lane >> 4) * 4;
        int cg = bn0 + wg_n * 64 + nf * 16 + lr;
        float* op = out + (size_t)rg * OUT_F + cg;
        op[0 * OUT_F] = (maccA[mf][nf][0] + bs_[nf]) + (maccM[m8][nf][0] + scl[nf]) * b0;
        op[1 * OUT_F] = (maccA[mf][nf][1] + bs_[nf]) + (maccM[m8][nf][1] + scl[nf]) * b1;
        op[2 * OUT_F] = (maccA[mf][nf][2] + bs_[nf]) + (maccM[m8][nf][2] + scl[nf]) * b2;
        op[3 * OUT_F] = (maccA[mf][nf][3] + bs_[nf]) + (maccM[m8][nf][3] + scl[nf]) * b3;
      }
  }
}

// ---------------- launch ----------------

extern "C" void kernel_launch(void* const* d_in, const int* in_sizes, int n_in,
                              void* d_out, int out_size, void* d_ws, size_t ws_size,
                              hipStream_t stream) {
  const float* input = (const float*)d_in[0];
  const int*   zm    = (const int*)d_in[1];
  const float* cb    = (const float*)d_in[2];
  const float* l1    = (const float*)d_in[3];
  const float* l2    = (const float*)d_in[4];
  const float* gs    = (const float*)d_in[5];
  const float* gb    = (const float*)d_in[6];
  const float* scale = (const float*)d_in[7];
  const float* bias  = (const float*)d_in[8];
  float* out = (float*)d_out;

  const size_t OFF_A  = 0;                                        // 64 MiB
  const size_t OFF_W  = OFF_A + (size_t)NTOK * IN_F * 2;          // 32 MiB
  const size_t OFF_L1 = OFF_W + (size_t)OUT_F * IN_F * 2;         // 1 MiB
  const size_t OFF_L2 = OFF_L1 + (size_t)LRANK * IN_F * 2;        // 2 MiB
  const size_t OFF_H  = OFF_L2 + (size_t)2 * OUT_F * LRANK * 2;   // 2 MiB
  const size_t OFF_BL = OFF_H + (size_t)NTOK * LRANK * 2;         // 64 MiB (bf16 packed)
  const size_t NEED   = OFF_BL + (size_t)NTOK * OUT_F * 2;
  if (ws_size < NEED) return;

  char* ws = (char*)d_ws;
  u16* A    = (u16*)(ws + OFF_A);
  u16* W    = (u16*)(ws + OFF_W);
  u16* L1b  = (u16*)(ws + OFF_L1);
  u16* L2b  = (u16*)(ws + OFF_L2);
  u16* H    = (u16*)(ws + OFF_H);
  uint2* Bl = (uint2*)(ws + OFF_BL);

  cvt_bf16_kernel<<<(NTOK * IN_F / 4) / 256, 256, 0, stream>>>(input, A, NTOK * IN_F / 4);
  cvt_bf16_kernel<<<(LRANK * IN_F / 4) / 256, 256, 0, stream>>>(l1, L1b, LRANK * IN_F / 4);
  cvt_bf16_kernel<<<(2 * OUT_F * LRANK / 4) / 256, 256, 0, stream>>>(l2, L2b, 2 * OUT_F * LRANK / 4);
  dequant_kernel<<<(OUT_F * IN_F / 4) / 256, 256, 0, stream>>>(zm, cb, gs, gb, W);

  gemm_hid<<<NTOK / 128, 256, 0, stream>>>(A, L1b, H);

  gemm_main<<<(NTOK / 256) * (OUT_F / 256), 512, 0, stream>>>(A, W, Bl);

  lr_apply<<<(NTOK / 256) * (OUT_F / 256), 512, 0, stream>>>(Bl, H, L2b, scale, bias, out);
}

// Round 8
// 377.770 us; speedup vs baseline: 1.8592x; 1.1307x over previous
//
#include <hip/hip_runtime.h>
#include <hip/hip_bf16.h>

#define IN_F   4096
#define OUT_F  4096
#define NTOK   8192
#define LRANK  128

typedef unsigned short u16;
typedef unsigned int u32;
typedef __attribute__((ext_vector_type(8))) __bf16 bf16x8;
typedef __attribute__((ext_vector_type(4))) float f32x4;

__device__ __forceinline__ u16 f2bf(float f) {
  union { float f; unsigned u; } a; a.f = f;
  return (u16)((a.u + 0x7fffu + ((a.u >> 16) & 1u)) >> 16);
}
__device__ __forceinline__ float bf2f(u16 b) {
  union { unsigned u; float f; } a; a.u = (u32)b << 16;
  return a.f;
}

// async global->LDS, 16B per lane. LDS dest is wave-uniform base + lane*16.
__device__ __forceinline__ void async_ld16(const void* g, void* l) {
  __builtin_amdgcn_global_load_lds(
      (__attribute__((address_space(1))) void*)(unsigned long long)g,
      (__attribute__((address_space(3))) void*)(unsigned int)(unsigned long long)l,
      16, 0, 0);
}

// ---------------- prep kernels ----------------

__global__ void cvt_bf16_kernel(const float* __restrict__ src, u16* __restrict__ dst, int n4) {
  int i = blockIdx.x * blockDim.x + threadIdx.x;
  if (i >= n4) return;
  float4 v = ((const float4*)src)[i];
  ushort4 o;
  o.x = f2bf(v.x); o.y = f2bf(v.y); o.z = f2bf(v.z); o.w = f2bf(v.w);
  ((ushort4*)dst)[i] = o;
}

// merged small converts (L1, L2)
__global__ void cvt_bf16_2_kernel(const float* __restrict__ s1, u16* __restrict__ d1, int n1,
                                  const float* __restrict__ s2, u16* __restrict__ d2, int n2) {
  int i = blockIdx.x * blockDim.x + threadIdx.x;
  const float* s; u16* d; int j;
  if (i < n1) { s = s1; d = d1; j = i; }
  else if (i < n1 + n2) { s = s2; d = d2; j = i - n1; }
  else return;
  float4 v = ((const float4*)s)[j];
  ushort4 o;
  o.x = f2bf(v.x); o.y = f2bf(v.y); o.z = f2bf(v.z); o.w = f2bf(v.w);
  ((ushort4*)d)[j] = o;
}

__global__ void dequant_kernel(const int* __restrict__ zm, const float* __restrict__ cb,
                               const float* __restrict__ gs, const float* __restrict__ gb,
                               u16* __restrict__ W) {
  int idx = blockIdx.x * blockDim.x + threadIdx.x;   // one thread per 4 weights
  if (idx >= OUT_F * IN_F / 4) return;
  int o = idx >> 10;
  int i = (idx & 1023) << 2;
  int row = ((o >> 6) << 6) + (i >> 6);
  const int* zp = zm + ((size_t)row << 12) + ((o & 63) << 6) + (i & 63);
  int4 z = *(const int4*)zp;
  const float* cr = cb + ((size_t)row << 8);
  int g = (o >> 3) * (IN_F / 8) + (i >> 3);
  float s = gs[g], b = gb[g];
  ushort4 w;
  w.x = f2bf(b + cr[z.x] * s);
  w.y = f2bf(b + cr[z.y] * s);
  w.z = f2bf(b + cr[z.z] * s);
  w.w = f2bf(b + cr[z.w] * s);
  *(ushort4*)(W + (size_t)idx * 4) = w;
}

// ---------------- hid GEMM, K-split x4 ----------------
// hid_part: block (mt, kc) computes partial H over K = [kc*1024, kc*1024+1024)
// for token rows mt*128..+128, stored f32 in Hp[kc][row][col].

__device__ __forceinline__ void stage_tile_128x32(const u16* __restrict__ g, int stride,
                                                  int row0, int col0,
                                                  u16* lbase, int wave, int lane) {
#pragma unroll
  for (int p = 0; p < 2; ++p) {
    int li_base = wave * 64 + p * 256;
    int li = li_base + lane;
    const u16* gaddr = g + (size_t)(row0 + (li >> 2)) * stride + col0 + ((li & 3) << 3);
    async_ld16(gaddr, lbase + li_base * 8);
  }
}

__global__ __launch_bounds__(256) void hid_part(const u16* __restrict__ A,
                                                const u16* __restrict__ L1,
                                                float* __restrict__ Hp) {
  __shared__ __align__(16) u16 lds[2 * 128 * 32];
  u16* ldsA = lds;
  u16* ldsB = lds + 128 * 32;

  int tid = threadIdx.x;
  int wave = tid >> 6, lane = tid & 63;
  int kc  = blockIdx.x & 3;
  int bm0 = (blockIdx.x >> 2) * 128;
  int kbase = kc * 1024;
  int wr = (wave >> 1) * 64, wc = (wave & 1) * 64;
  int lrow = lane & 15, lk = (lane >> 4) * 8;

  f32x4 acc[4][4];
#pragma unroll
  for (int m = 0; m < 4; ++m)
#pragma unroll
    for (int n = 0; n < 4; ++n)
#pragma unroll
      for (int v = 0; v < 4; ++v) acc[m][n][v] = 0.f;

  for (int kt = 0; kt < 32; ++kt) {
    int k0 = kbase + kt * 32;
    stage_tile_128x32(A, IN_F, bm0, k0, ldsA, wave, lane);
    stage_tile_128x32(L1, IN_F, 0, k0, ldsB, wave, lane);
    __syncthreads();
    bf16x8 af[4], bfr[4];
#pragma unroll
    for (int m = 0; m < 4; ++m)
      af[m] = *(const bf16x8*)&ldsA[(wr + m * 16 + lrow) * 32 + lk];
#pragma unroll
    for (int n = 0; n < 4; ++n)
      bfr[n] = *(const bf16x8*)&ldsB[(wc + n * 16 + lrow) * 32 + lk];
#pragma unroll
    for (int m = 0; m < 4; ++m)
#pragma unroll
      for (int n = 0; n < 4; ++n)
        acc[m][n] = __builtin_amdgcn_mfma_f32_16x16x32_bf16(af[m], bfr[n], acc[m][n], 0, 0, 0);
    __syncthreads();
  }

  float* Hpk = Hp + (size_t)kc * NTOK * LRANK;
  int lrow4 = (lane >> 4) * 4;
#pragma unroll
  for (int m = 0; m < 4; ++m)
#pragma unroll
    for (int n = 0; n < 4; ++n)
#pragma unroll
      for (int v = 0; v < 4; ++v) {
        int rg = bm0 + wr + m * 16 + lrow4 + v;
        int cg = wc + n * 16 + lrow;
        Hpk[(size_t)rg * LRANK + cg] = acc[m][n][v];
      }
}

__global__ void hid_reduce(const float* __restrict__ Hp, u16* __restrict__ H) {
  int i = blockIdx.x * blockDim.x + threadIdx.x;   // one thread per 4 elems
  if (i >= NTOK * LRANK / 4) return;
  const size_t stride = (size_t)NTOK * LRANK;
  float4 s0 = ((const float4*)Hp)[i];
  float4 s1 = ((const float4*)(Hp + stride))[i];
  float4 s2 = ((const float4*)(Hp + 2 * stride))[i];
  float4 s3 = ((const float4*)(Hp + 3 * stride))[i];
  ushort4 o;
  o.x = f2bf(s0.x + s1.x + s2.x + s3.x);
  o.y = f2bf(s0.y + s1.y + s2.y + s3.y);
  o.z = f2bf(s0.z + s1.z + s2.z + s3.z);
  o.w = f2bf(s0.w + s1.w + s2.w + s3.w);
  ((ushort4*)H)[i] = o;
}

// ---------------- main GEMM: 256x256 tile, BK=64, 8-phase schedule ----------------
// Pure GEMM (low-rank epilogue unfused -> lr_apply). Writes baseline as packed
// bf16 in NATIVE per-thread layout: uint2 at ((bid*8+wave)*32 + mf*4+nf)*64+lane.

#define MFMA_QUAD(mh, nh)                                                        \
  _Pragma("unroll") for (int mf = 0; mf < 4; ++mf)                               \
  _Pragma("unroll") for (int nf = 0; nf < 2; ++nf)                               \
  _Pragma("unroll") for (int ks = 0; ks < 2; ++ks)                               \
    acc[(mh)*4 + mf][(nh)*2 + nf] = __builtin_amdgcn_mfma_f32_16x16x32_bf16(     \
        af[mf][ks], bfr[nh][nf][ks], acc[(mh)*4 + mf][(nh)*2 + nf], 0, 0, 0);

#define PHASE_MID                                          \
  __builtin_amdgcn_s_barrier();                            \
  asm volatile("s_waitcnt lgkmcnt(0)" ::: "memory");       \
  __builtin_amdgcn_sched_barrier(0);                       \
  __builtin_amdgcn_s_setprio(1);

#define PHASE_END                                          \
  __builtin_amdgcn_s_setprio(0);                           \
  __builtin_amdgcn_s_barrier();

#define PHASE_END_VM                                       \
  __builtin_amdgcn_s_setprio(0);                           \
  asm volatile("s_waitcnt vmcnt(4)" ::: "memory");         \
  __builtin_amdgcn_s_barrier();

#define PHASE_END_VM0                                      \
  __builtin_amdgcn_s_setprio(0);                           \
  asm volatile("s_waitcnt vmcnt(0)" ::: "memory");         \
  __builtin_amdgcn_s_barrier();

// LDS regions (bytes): buf b at b*65536; A halves +0,+16384; B halves +32768,+49152
#define LAB(b, h) ((char*)lds + (b) * 65536 + (h) * 16384)
#define LBB(b, h) ((char*)lds + (b) * 65536 + 32768 + (h) * 16384)

#define STG_K(gbase, lreg) do {                               \
    async_ld16((gbase) + gK0, (lreg) + ldst0);                \
    async_ld16((gbase) + gK1, (lreg) + ldst0 + 8192); } while (0)
#define STG_L(gbase, lreg) do {                               \
    async_ld16((gbase) + gL0, (lreg) + ldst0);                \
    async_ld16((gbase) + gL1, (lreg) + ldst0 + 8192); } while (0)

#define LDF(p, byteoff, lb) (*(const bf16x8*)((p) + (byteoff) + (lb)))

__global__ __launch_bounds__(512)
__attribute__((amdgpu_waves_per_eu(2, 2)))
void gemm_main(const u16* __restrict__ A,
               const u16* __restrict__ W,
               uint2* __restrict__ Bl) {
  __shared__ __align__(16) u16 lds[65536];   // 128 KiB

  const int tid = threadIdx.x;
  const int lane = tid & 63, wave = tid >> 6;
  const int wg_m = wave >> 2;
  const int lr = lane & 15;

  // bijective XCD swizzle (nwg=512, 512%8==0)
  int bid = blockIdx.x;
  int swz = (bid & 7) * 64 + (bid >> 3);
  const int bn0 = (swz & 15) * 256;
  const int bm0 = (swz >> 4) * 256;

  // per-lane staging constants
  const int row_c = tid >> 3;
  const int xslot = ((tid & 7) ^ (row_c & 7)) << 3;
  const int gK0 = row_c * IN_F + xslot;
  const int gK1 = gK0 + 64 * IN_F;
  const int ldst0 = (tid & ~63) * 16;

  // per-lane frag-read constants
  const int lb0 = (lr << 7) | ((((lane >> 4)) ^ (lr & 7)) << 4);
  const int lb1 = (lr << 7) | (((4 | (lane >> 4)) ^ (lr & 7)) << 4);

  const u16* baseA0 = A + (size_t)bm0 * IN_F;
  const u16* baseA1 = A + (size_t)(bm0 + 128) * IN_F;
  const u16* baseW0 = W + (size_t)bn0 * IN_F;
  const u16* baseW1 = W + (size_t)(bn0 + 128) * IN_F;

  const int wg_n = wave & 3;
  const int b_row0 = (wg_n & 1) * 64;
  const char* pA0 = LAB(0, wg_m);
  const char* pA1 = LAB(1, wg_m);
  const char* pB0 = LBB(0, wg_n >> 1) + b_row0 * 128;
  const char* pB1 = LBB(1, wg_n >> 1) + b_row0 * 128;

  f32x4 acc[8][4];
#pragma unroll
  for (int m = 0; m < 8; ++m)
#pragma unroll
    for (int n = 0; n < 4; ++n)
#pragma unroll
      for (int v = 0; v < 4; ++v) acc[m][n][v] = 0.f;

  // ---- prologue: kt0 -> buf0 (B0,B1,A0,A1), kt1.B -> buf1 ----
  STG_K(baseW0, LBB(0, 0));
  STG_K(baseW1, LBB(0, 1));
  STG_K(baseA0, LAB(0, 0));
  STG_K(baseA1, LAB(0, 1));
  STG_K(baseW0 + 64, LBB(1, 0));
  STG_K(baseW1 + 64, LBB(1, 1));
  asm volatile("s_waitcnt vmcnt(4)" ::: "memory");
  __builtin_amdgcn_s_barrier();

  bf16x8 af[4][2];
  bf16x8 bfr[2][2][2];

  for (int u = 0; u < 31; ++u) {
    const int c1k = (2 * u + 1) * 64;
    const int n0k = (2 * u + 2) * 64;
    const int n1k = (2 * u + 3) * 64;

    // ---- P1: quad(0,0) on buf0 ----
#pragma unroll
    for (int mf = 0; mf < 4; ++mf) {
      af[mf][0] = LDF(pA0, mf * 2048, lb0);
      af[mf][1] = LDF(pA0, mf * 2048, lb1);
    }
#pragma unroll
    for (int nf = 0; nf < 2; ++nf) {
      bfr[0][nf][0] = LDF(pB0, nf * 2048, lb0);
      bfr[0][nf][1] = LDF(pB0, nf * 2048, lb1);
    }
    STG_K(baseA0 + c1k, LAB(1, 0));
    PHASE_MID; MFMA_QUAD(0, 0); PHASE_END;

    // ---- P2: quad(0,1) ----
#pragma unroll
    for (int nf = 0; nf < 2; ++nf) {
      bfr[1][nf][0] = LDF(pB0, 4096 + nf * 2048, lb0);
      bfr[1][nf][1] = LDF(pB0, 4096 + nf * 2048, lb1);
    }
    STG_K(baseA1 + c1k, LAB(1, 1));
    PHASE_MID; MFMA_QUAD(0, 1); PHASE_END;

    // ---- P3: quad(1,1) ----
#pragma unroll
    for (int mf = 0; mf < 4; ++mf) {
      af[mf][0] = LDF(pA0, 8192 + mf * 2048, lb0);
      af[mf][1] = LDF(pA0, 8192 + mf * 2048, lb1);
    }
    STG_K(baseW0 + n0k, LBB(0, 0));
    PHASE_MID; MFMA_QUAD(1, 1); PHASE_END;

    // ---- P4: quad(1,0) ----
    STG_K(baseW1 + n0k, LBB(0, 1));
    PHASE_MID; MFMA_QUAD(1, 0); PHASE_END_VM;

    // ---- P5: quad(0,0) on buf1 ----
#pragma unroll
    for (int mf = 0; mf < 4; ++mf) {
      af[mf][0] = LDF(pA1, mf * 2048, lb0);
      af[mf][1] = LDF(pA1, mf * 2048, lb1);
    }
#pragma unroll
    for (int nf = 0; nf < 2; ++nf) {
      bfr[0][nf][0] = LDF(pB1, nf * 2048, lb0);
      bfr[0][nf][1] = LDF(pB1, nf * 2048, lb1);
    }
    STG_K(baseA0 + n0k, LAB(0, 0));
    PHASE_MID; MFMA_QUAD(0, 0); PHASE_END;

    // ---- P6: quad(0,1) ----
#pragma unroll
    for (int nf = 0; nf < 2; ++nf) {
      bfr[1][nf][0] = LDF(pB1, 4096 + nf * 2048, lb0);
      bfr[1][nf][1] = LDF(pB1, 4096 + nf * 2048, lb1);
    }
    STG_K(baseA1 + n0k, LAB(0, 1));
    PHASE_MID; MFMA_QUAD(0, 1); PHASE_END;

    // ---- P7: quad(1,1) ----
#pragma unroll
    for (int mf = 0; mf < 4; ++mf) {
      af[mf][0] = LDF(pA1, 8192 + mf * 2048, lb0);
      af[mf][1] = LDF(pA1, 8192 + mf * 2048, lb1);
    }
    STG_K(baseW0 + n1k, LBB(1, 0));
    PHASE_MID; MFMA_QUAD(1, 1); PHASE_END;

    // ---- P8: quad(1,0) ----
    STG_K(baseW1 + n1k, LBB(1, 1));
    PHASE_MID; MFMA_QUAD(1, 0); PHASE_END_VM;
  }

  // ---- peeled tail (u=31): only buf1.A (kt63) staged; no next-tile loads ----
  {
    const int c1k = 63 * 64;

    // P1
#pragma unroll
    for (int mf = 0; mf < 4; ++mf) {
      af[mf][0] = LDF(pA0, mf * 2048, lb0);
      af[mf][1] = LDF(pA0, mf * 2048, lb1);
    }
#pragma unroll
    for (int nf = 0; nf < 2; ++nf) {
      bfr[0][nf][0] = LDF(pB0, nf * 2048, lb0);
      bfr[0][nf][1] = LDF(pB0, nf * 2048, lb1);
    }
    STG_K(baseA0 + c1k, LAB(1, 0));
    PHASE_MID; MFMA_QUAD(0, 0); PHASE_END;

    // P2
#pragma unroll
    for (int nf = 0; nf < 2; ++nf) {
      bfr[1][nf][0] = LDF(pB0, 4096 + nf * 2048, lb0);
      bfr[1][nf][1] = LDF(pB0, 4096 + nf * 2048, lb1);
    }
    STG_K(baseA1 + c1k, LAB(1, 1));
    PHASE_MID; MFMA_QUAD(0, 1); PHASE_END;

    // P3
#pragma unroll
    for (int mf = 0; mf < 4; ++mf) {
      af[mf][0] = LDF(pA0, 8192 + mf * 2048, lb0);
      af[mf][1] = LDF(pA0, 8192 + mf * 2048, lb1);
    }
    PHASE_MID; MFMA_QUAD(1, 1); PHASE_END;

    // P4: only 4 loads outstanding -> must drain fully before buf1.A reads
    PHASE_MID; MFMA_QUAD(1, 0); PHASE_END_VM0;

    // P5
#pragma unroll
    for (int mf = 0; mf < 4; ++mf) {
      af[mf][0] = LDF(pA1, mf * 2048, lb0);
      af[mf][1] = LDF(pA1, mf * 2048, lb1);
    }
#pragma unroll
    for (int nf = 0; nf < 2; ++nf) {
      bfr[0][nf][0] = LDF(pB1, nf * 2048, lb0);
      bfr[0][nf][1] = LDF(pB1, nf * 2048, lb1);
    }
    PHASE_MID; MFMA_QUAD(0, 0); PHASE_END;

    // P6
#pragma unroll
    for (int nf = 0; nf < 2; ++nf) {
      bfr[1][nf][0] = LDF(pB1, 4096 + nf * 2048, lb0);
      bfr[1][nf][1] = LDF(pB1, 4096 + nf * 2048, lb1);
    }
    PHASE_MID; MFMA_QUAD(0, 1); PHASE_END;

    // P7
#pragma unroll
    for (int mf = 0; mf < 4; ++mf) {
      af[mf][0] = LDF(pA1, 8192 + mf * 2048, lb0);
      af[mf][1] = LDF(pA1, 8192 + mf * 2048, lb1);
    }
    PHASE_MID; MFMA_QUAD(1, 1); PHASE_END;

    // P8
    PHASE_MID; MFMA_QUAD(1, 0); PHASE_END;
  }

  // ---- store baseline: packed bf16, native per-thread layout ----
  const size_t tbase = ((size_t)bid * 8 + wave) * 32;
#pragma unroll
  for (int mf = 0; mf < 8; ++mf)
#pragma unroll
    for (int nf = 0; nf < 4; ++nf) {
      f32x4 a = acc[mf][nf];
      uint2 pk;
      pk.x = (u32)f2bf(a[0]) | ((u32)f2bf(a[1]) << 16);
      pk.y = (u32)f2bf(a[2]) | ((u32)f2bf(a[3]) << 16);
      Bl[(tbase + mf * 4 + nf) * 64 + lane] = pk;
    }
}

// ---------------- lr_apply: out = (H·L2a + bias) + (H·L2m + scale) * baseline ----------------
// Same geometry/swizzle as gemm_main; reads baseline in native layout.

__global__ __launch_bounds__(512)
void lr_apply(const uint2* __restrict__ Bl,
              const u16* __restrict__ H,
              const u16* __restrict__ L2,
              const float* __restrict__ scale,
              const float* __restrict__ bias,
              float* __restrict__ out) {
  __shared__ __align__(16) u16 lds[65536];   // 128 KiB

  const int tid = threadIdx.x;
  const int lane = tid & 63, wave = tid >> 6;
  const int wg_m = wave >> 2, wg_n = wave & 3;
  const int lr = lane & 15;

  int bid = blockIdx.x;
  int swz = (bid & 7) * 64 + (bid >> 3);
  const int bn0 = (swz & 15) * 256;
  const int bm0 = (swz >> 4) * 256;

  const int row_c = tid >> 3;
  const int xslot = ((tid & 7) ^ (row_c & 7)) << 3;
  const int gL0 = row_c * LRANK + xslot;
  const int gL1 = gL0 + 64 * LRANK;
  const int ldst0 = (tid & ~63) * 16;

  const int lb0 = (lr << 7) | ((((lane >> 4)) ^ (lr & 7)) << 4);
  const int lb1 = (lr << 7) | (((4 | (lane >> 4)) ^ (lr & 7)) << 4);

  float scl[4], bs_[4];
#pragma unroll
  for (int nf = 0; nf < 4; ++nf) {
    int cg = bn0 + wg_n * 64 + nf * 16 + lr;
    scl[nf] = scale[cg];
    bs_[nf] = bias[cg];
  }

  // stage H (4 halves) + L2m (4 halves):
  // H(s,h) = s*32768 + h*16384 ; L2(s,h) = 65536 + s*32768 + h*16384
  {
    const u16* baseH0 = H + (size_t)bm0 * LRANK;
    const u16* baseH1 = H + (size_t)(bm0 + 128) * LRANK;
    const u16* baseL0 = L2 + (size_t)bn0 * LRANK;
    const u16* baseL1 = L2 + (size_t)(bn0 + 128) * LRANK;
    STG_L(baseH0,      (char*)lds + 0);
    STG_L(baseH1,      (char*)lds + 16384);
    STG_L(baseH0 + 64, (char*)lds + 32768);
    STG_L(baseH1 + 64, (char*)lds + 49152);
    STG_L(baseL0,      (char*)lds + 65536);
    STG_L(baseL1,      (char*)lds + 81920);
    STG_L(baseL0 + 64, (char*)lds + 98304);
    STG_L(baseL1 + 64, (char*)lds + 114688);
  }
  __syncthreads();

  const char* pH = (char*)lds + wg_m * 16384;
  const char* pL = (char*)lds + 65536 + (wg_n >> 1) * 16384 + (wg_n & 1) * 8192;

  // full multiplicative accumulator
  f32x4 maccM[8][4];
#pragma unroll
  for (int m = 0; m < 8; ++m)
#pragma unroll
    for (int n = 0; n < 4; ++n)
#pragma unroll
      for (int v = 0; v < 4; ++v) maccM[m][n][v] = 0.f;

#pragma unroll
  for (int kc = 0; kc < 4; ++kc) {
    const int sb = (kc >> 1) * 32768;
    const int lb = (kc & 1) ? lb1 : lb0;
    bf16x8 lf[4];
#pragma unroll
    for (int nf = 0; nf < 4; ++nf)
      lf[nf] = LDF(pL + sb, nf * 2048, lb);
#pragma unroll
    for (int mf = 0; mf < 8; ++mf) {
      bf16x8 hf = LDF(pH + sb, mf * 2048, lb);
#pragma unroll
      for (int nf = 0; nf < 4; ++nf)
        maccM[mf][nf] = __builtin_amdgcn_mfma_f32_16x16x32_bf16(hf, lf[nf], maccM[mf][nf], 0, 0, 0);
    }
  }

  // restage L2 additive rows over the L2m region
  __syncthreads();
  {
    const u16* baseL0 = L2 + (size_t)(OUT_F + bn0) * LRANK;
    const u16* baseL1 = L2 + (size_t)(OUT_F + bn0 + 128) * LRANK;
    STG_L(baseL0,      (char*)lds + 65536);
    STG_L(baseL1,      (char*)lds + 81920);
    STG_L(baseL0 + 64, (char*)lds + 98304);
    STG_L(baseL1 + 64, (char*)lds + 114688);
  }
  __syncthreads();

  // additive pass chunked by m-quarter, immediate apply + store
  const size_t tbase = ((size_t)bid * 8 + wave) * 32;
#pragma unroll
  for (int mq = 0; mq < 4; ++mq) {
    f32x4 maccA[2][4];
#pragma unroll
    for (int m = 0; m < 2; ++m)
#pragma unroll
      for (int n = 0; n < 4; ++n)
#pragma unroll
        for (int v = 0; v < 4; ++v) maccA[m][n][v] = 0.f;

#pragma unroll
    for (int kc = 0; kc < 4; ++kc) {
      const int sb = (kc >> 1) * 32768;
      const int lb = (kc & 1) ? lb1 : lb0;
      bf16x8 lf[4];
#pragma unroll
      for (int nf = 0; nf < 4; ++nf)
        lf[nf] = LDF(pL + sb, nf * 2048, lb);
#pragma unroll
      for (int mf = 0; mf < 2; ++mf) {
        bf16x8 hf = LDF(pH + sb, (mq * 2 + mf) * 2048, lb);
#pragma unroll
        for (int nf = 0; nf < 4; ++nf)
          maccA[mf][nf] = __builtin_amdgcn_mfma_f32_16x16x32_bf16(hf, lf[nf], maccA[mf][nf], 0, 0, 0);
      }
    }

#pragma unroll
    for (int mf = 0; mf < 2; ++mf)
#pragma unroll
      for (int nf = 0; nf < 4; ++nf) {
        int m8 = mq * 2 + mf;
        uint2 pk = Bl[(tbase + m8 * 4 + nf) * 64 + lane];
        float b0 = bf2f((u16)(pk.x & 0xffff));
        float b1 = bf2f((u16)(pk.x >> 16));
        float b2 = bf2f((u16)(pk.y & 0xffff));
        float b3 = bf2f((u16)(pk.y >> 16));
        int rg = bm0 + wg_m * 128 + m8 * 16 + (lane >> 4) * 4;
        int cg = bn0 + wg_n * 64 + nf * 16 + lr;
        float* op = out + (size_t)rg * OUT_F + cg;
        op[0 * OUT_F] = (maccA[mf][nf][0] + bs_[nf]) + (maccM[m8][nf][0] + scl[nf]) * b0;
        op[1 * OUT_F] = (maccA[mf][nf][1] + bs_[nf]) + (maccM[m8][nf][1] + scl[nf]) * b1;
        op[2 * OUT_F] = (maccA[mf][nf][2] + bs_[nf]) + (maccM[m8][nf][2] + scl[nf]) * b2;
        op[3 * OUT_F] = (maccA[mf][nf][3] + bs_[nf]) + (maccM[m8][nf][3] + scl[nf]) * b3;
      }
  }
}

// ---------------- launch ----------------

extern "C" void kernel_launch(void* const* d_in, const int* in_sizes, int n_in,
                              void* d_out, int out_size, void* d_ws, size_t ws_size,
                              hipStream_t stream) {
  const float* input = (const float*)d_in[0];
  const int*   zm    = (const int*)d_in[1];
  const float* cb    = (const float*)d_in[2];
  const float* l1    = (const float*)d_in[3];
  const float* l2    = (const float*)d_in[4];
  const float* gs    = (const float*)d_in[5];
  const float* gb    = (const float*)d_in[6];
  const float* scale = (const float*)d_in[7];
  const float* bias  = (const float*)d_in[8];
  float* out = (float*)d_out;

  const size_t OFF_A  = 0;                                        // 64 MiB
  const size_t OFF_W  = OFF_A + (size_t)NTOK * IN_F * 2;          // 32 MiB
  const size_t OFF_L1 = OFF_W + (size_t)OUT_F * IN_F * 2;         // 1 MiB
  const size_t OFF_L2 = OFF_L1 + (size_t)LRANK * IN_F * 2;        // 2 MiB
  const size_t OFF_H  = OFF_L2 + (size_t)2 * OUT_F * LRANK * 2;   // 2 MiB
  const size_t OFF_BL = OFF_H + (size_t)NTOK * LRANK * 2;         // 64 MiB (bf16 packed)
  const size_t NEED   = OFF_BL + (size_t)NTOK * OUT_F * 2;
  if (ws_size < NEED) return;

  char* ws = (char*)d_ws;
  u16* A    = (u16*)(ws + OFF_A);
  u16* W    = (u16*)(ws + OFF_W);
  u16* L1b  = (u16*)(ws + OFF_L1);
  u16* L2b  = (u16*)(ws + OFF_L2);
  u16* H    = (u16*)(ws + OFF_H);
  uint2* Bl = (uint2*)(ws + OFF_BL);
  // Hp (16 MiB f32 partials) overlays the Bl region: Hp is dead before
  // gemm_main writes Bl (serial stream), so no conflict.
  float* Hp = (float*)(ws + OFF_BL);

  cvt_bf16_kernel<<<(NTOK * IN_F / 4) / 256, 256, 0, stream>>>(input, A, NTOK * IN_F / 4);
  cvt_bf16_2_kernel<<<((LRANK * IN_F + 2 * OUT_F * LRANK) / 4 + 255) / 256, 256, 0, stream>>>(
      l1, L1b, LRANK * IN_F / 4, l2, L2b, 2 * OUT_F * LRANK / 4);
  dequant_kernel<<<(OUT_F * IN_F / 4) / 256, 256, 0, stream>>>(zm, cb, gs, gb, W);

  hid_part<<<4 * (NTOK / 128), 256, 0, stream>>>(A, L1b, Hp);
  hid_reduce<<<(NTOK * LRANK / 4) / 256, 256, 0, stream>>>(Hp, H);

  gemm_main<<<(NTOK / 256) * (OUT_F / 256), 512, 0, stream>>>(A, W, Bl);

  lr_apply<<<(NTOK / 256) * (OUT_F / 256), 512, 0, stream>>>(Bl, H, L2b, scale, bias, out);
}

// Round 9
// 374.883 us; speedup vs baseline: 1.8736x; 1.0077x over previous
//
#include <hip/hip_runtime.h>
#include <hip/hip_bf16.h>

#define IN_F   4096
#define OUT_F  4096
#define NTOK   8192
#define LRANK  128

typedef unsigned short u16;
typedef unsigned int u32;
typedef __attribute__((ext_vector_type(8))) __bf16 bf16x8;
typedef __attribute__((ext_vector_type(4))) float f32x4;

__device__ __forceinline__ u16 f2bf(float f) {
  union { float f; unsigned u; } a; a.f = f;
  return (u16)((a.u + 0x7fffu + ((a.u >> 16) & 1u)) >> 16);
}
__device__ __forceinline__ float bf2f(u16 b) {
  union { unsigned u; float f; } a; a.u = (u32)b << 16;
  return a.f;
}

// async global->LDS, 16B per lane. LDS dest is wave-uniform base + lane*16.
__device__ __forceinline__ void async_ld16(const void* g, void* l) {
  __builtin_amdgcn_global_load_lds(
      (__attribute__((address_space(1))) void*)(unsigned long long)g,
      (__attribute__((address_space(3))) void*)(unsigned int)(unsigned long long)l,
      16, 0, 0);
}

// ---------------- prep kernels ----------------

// merged small converts (L1, L2)
__global__ void cvt_bf16_2_kernel(const float* __restrict__ s1, u16* __restrict__ d1, int n1,
                                  const float* __restrict__ s2, u16* __restrict__ d2, int n2) {
  int i = blockIdx.x * blockDim.x + threadIdx.x;
  const float* s; u16* d; int j;
  if (i < n1) { s = s1; d = d1; j = i; }
  else if (i < n1 + n2) { s = s2; d = d2; j = i - n1; }
  else return;
  float4 v = ((const float4*)s)[j];
  ushort4 o;
  o.x = f2bf(v.x); o.y = f2bf(v.y); o.z = f2bf(v.z); o.w = f2bf(v.w);
  ((ushort4*)d)[j] = o;
}

__global__ void dequant_kernel(const int* __restrict__ zm, const float* __restrict__ cb,
                               const float* __restrict__ gs, const float* __restrict__ gb,
                               u16* __restrict__ W) {
  int idx = blockIdx.x * blockDim.x + threadIdx.x;   // one thread per 4 weights
  if (idx >= OUT_F * IN_F / 4) return;
  int o = idx >> 10;
  int i = (idx & 1023) << 2;
  int row = ((o >> 6) << 6) + (i >> 6);
  const int* zp = zm + ((size_t)row << 12) + ((o & 63) << 6) + (i & 63);
  int4 z = *(const int4*)zp;
  const float* cr = cb + ((size_t)row << 8);
  int g = (o >> 3) * (IN_F / 8) + (i >> 3);
  float s = gs[g], b = gb[g];
  ushort4 w;
  w.x = f2bf(b + cr[z.x] * s);
  w.y = f2bf(b + cr[z.y] * s);
  w.z = f2bf(b + cr[z.z] * s);
  w.w = f2bf(b + cr[z.w] * s);
  *(ushort4*)(W + (size_t)idx * 4) = w;
}

// ---------------- hid GEMM, K-split x4, FUSED input conversion ----------------
// Block (mt, kc): token rows mt*128..+128, K cols kc*1024..+1024.
// Reads input f32 directly; converts to bf16 in-reg; writes LDS (for its MFMA)
// AND the global A buffer (each block owns a disjoint chunk -> A fully written).

__device__ __forceinline__ void stage_tile_128x32(const u16* __restrict__ g, int stride,
                                                  int row0, int col0,
                                                  u16* lbase, int wave, int lane) {
#pragma unroll
  for (int p = 0; p < 2; ++p) {
    int li_base = wave * 64 + p * 256;
    int li = li_base + lane;
    const u16* gaddr = g + (size_t)(row0 + (li >> 2)) * stride + col0 + ((li & 3) << 3);
    async_ld16(gaddr, lbase + li_base * 8);
  }
}

__global__ __launch_bounds__(256) void hid_part(const float* __restrict__ input,
                                                u16* __restrict__ A,
                                                const u16* __restrict__ L1,
                                                float* __restrict__ Hp) {
  __shared__ __align__(16) u16 lds[2 * 128 * 32];
  u16* ldsA = lds;
  u16* ldsB = lds + 128 * 32;

  int tid = threadIdx.x;
  int wave = tid >> 6, lane = tid & 63;
  int kc  = blockIdx.x & 3;
  int bm0 = (blockIdx.x >> 2) * 128;
  int kbase = kc * 1024;
  int wr = (wave >> 1) * 64, wc = (wave & 1) * 64;
  int lrow = lane & 15, lk = (lane >> 4) * 8;

  // conversion-staging coords: 2 threads per row, 16 cols each
  const int crow = tid >> 1;
  const int c16  = (tid & 1) * 16;

  f32x4 acc[4][4];
#pragma unroll
  for (int m = 0; m < 4; ++m)
#pragma unroll
    for (int n = 0; n < 4; ++n)
#pragma unroll
      for (int v = 0; v < 4; ++v) acc[m][n][v] = 0.f;

  for (int kt = 0; kt < 32; ++kt) {
    int k0 = kbase + kt * 32;

    // L1 tile via async gload_lds (bf16 already)
    stage_tile_128x32(L1, IN_F, 0, k0, ldsB, wave, lane);

    // A tile: f32 load -> bf16 convert -> LDS + global side-write
    {
      const float* ip = input + (size_t)(bm0 + crow) * IN_F + k0 + c16;
      float4 v0 = ((const float4*)ip)[0];
      float4 v1 = ((const float4*)ip)[1];
      float4 v2 = ((const float4*)ip)[2];
      float4 v3 = ((const float4*)ip)[3];
      ushort4 o0, o1, o2, o3;
      o0.x = f2bf(v0.x); o0.y = f2bf(v0.y); o0.z = f2bf(v0.z); o0.w = f2bf(v0.w);
      o1.x = f2bf(v1.x); o1.y = f2bf(v1.y); o1.z = f2bf(v1.z); o1.w = f2bf(v1.w);
      o2.x = f2bf(v2.x); o2.y = f2bf(v2.y); o2.z = f2bf(v2.z); o2.w = f2bf(v2.w);
      o3.x = f2bf(v3.x); o3.y = f2bf(v3.y); o3.z = f2bf(v3.z); o3.w = f2bf(v3.w);
      u16* lp = &ldsA[crow * 32 + c16];
      ((ushort4*)lp)[0] = o0; ((ushort4*)lp)[1] = o1;
      ((ushort4*)lp)[2] = o2; ((ushort4*)lp)[3] = o3;
      u16* gp = A + (size_t)(bm0 + crow) * IN_F + k0 + c16;
      ((ushort4*)gp)[0] = o0; ((ushort4*)gp)[1] = o1;
      ((ushort4*)gp)[2] = o2; ((ushort4*)gp)[3] = o3;
    }
    __syncthreads();

    bf16x8 af[4], bfr[4];
#pragma unroll
    for (int m = 0; m < 4; ++m)
      af[m] = *(const bf16x8*)&ldsA[(wr + m * 16 + lrow) * 32 + lk];
#pragma unroll
    for (int n = 0; n < 4; ++n)
      bfr[n] = *(const bf16x8*)&ldsB[(wc + n * 16 + lrow) * 32 + lk];
#pragma unroll
    for (int m = 0; m < 4; ++m)
#pragma unroll
      for (int n = 0; n < 4; ++n)
        acc[m][n] = __builtin_amdgcn_mfma_f32_16x16x32_bf16(af[m], bfr[n], acc[m][n], 0, 0, 0);
    __syncthreads();
  }

  float* Hpk = Hp + (size_t)kc * NTOK * LRANK;
  int lrow4 = (lane >> 4) * 4;
#pragma unroll
  for (int m = 0; m < 4; ++m)
#pragma unroll
    for (int n = 0; n < 4; ++n)
#pragma unroll
      for (int v = 0; v < 4; ++v) {
        int rg = bm0 + wr + m * 16 + lrow4 + v;
        int cg = wc + n * 16 + lrow;
        Hpk[(size_t)rg * LRANK + cg] = acc[m][n][v];
      }
}

__global__ void hid_reduce(const float* __restrict__ Hp, u16* __restrict__ H) {
  int i = blockIdx.x * blockDim.x + threadIdx.x;   // one thread per 4 elems
  if (i >= NTOK * LRANK / 4) return;
  const size_t stride = (size_t)NTOK * LRANK;
  float4 s0 = ((const float4*)Hp)[i];
  float4 s1 = ((const float4*)(Hp + stride))[i];
  float4 s2 = ((const float4*)(Hp + 2 * stride))[i];
  float4 s3 = ((const float4*)(Hp + 3 * stride))[i];
  ushort4 o;
  o.x = f2bf(s0.x + s1.x + s2.x + s3.x);
  o.y = f2bf(s0.y + s1.y + s2.y + s3.y);
  o.z = f2bf(s0.z + s1.z + s2.z + s3.z);
  o.w = f2bf(s0.w + s1.w + s2.w + s3.w);
  ((ushort4*)H)[i] = o;
}

// ---------------- main GEMM: 256x256 tile, BK=64, 8-phase schedule ----------------
// Pure GEMM (low-rank epilogue unfused -> lr_apply). Writes baseline as packed
// bf16 in NATIVE per-thread layout: uint2 at ((bid*8+wave)*32 + mf*4+nf)*64+lane.

#define MFMA_QUAD(mh, nh)                                                        \
  _Pragma("unroll") for (int mf = 0; mf < 4; ++mf)                               \
  _Pragma("unroll") for (int nf = 0; nf < 2; ++nf)                               \
  _Pragma("unroll") for (int ks = 0; ks < 2; ++ks)                               \
    acc[(mh)*4 + mf][(nh)*2 + nf] = __builtin_amdgcn_mfma_f32_16x16x32_bf16(     \
        af[mf][ks], bfr[nh][nf][ks], acc[(mh)*4 + mf][(nh)*2 + nf], 0, 0, 0);

#define PHASE_MID                                          \
  __builtin_amdgcn_s_barrier();                            \
  asm volatile("s_waitcnt lgkmcnt(0)" ::: "memory");       \
  __builtin_amdgcn_sched_barrier(0);                       \
  __builtin_amdgcn_s_setprio(1);

#define PHASE_END                                          \
  __builtin_amdgcn_s_setprio(0);                           \
  __builtin_amdgcn_s_barrier();

#define PHASE_END_VM                                       \
  __builtin_amdgcn_s_setprio(0);                           \
  asm volatile("s_waitcnt vmcnt(4)" ::: "memory");         \
  __builtin_amdgcn_s_barrier();

#define PHASE_END_VM0                                      \
  __builtin_amdgcn_s_setprio(0);                           \
  asm volatile("s_waitcnt vmcnt(0)" ::: "memory");         \
  __builtin_amdgcn_s_barrier();

// LDS regions (bytes): buf b at b*65536; A halves +0,+16384; B halves +32768,+49152
#define LAB(b, h) ((char*)lds + (b) * 65536 + (h) * 16384)
#define LBB(b, h) ((char*)lds + (b) * 65536 + 32768 + (h) * 16384)

#define STG_K(gbase, lreg) do {                               \
    async_ld16((gbase) + gK0, (lreg) + ldst0);                \
    async_ld16((gbase) + gK1, (lreg) + ldst0 + 8192); } while (0)
#define STG_L(gbase, lreg) do {                               \
    async_ld16((gbase) + gL0, (lreg) + ldst0);                \
    async_ld16((gbase) + gL1, (lreg) + ldst0 + 8192); } while (0)

#define LDF(p, byteoff, lb) (*(const bf16x8*)((p) + (byteoff) + (lb)))

__global__ __launch_bounds__(512)
__attribute__((amdgpu_waves_per_eu(2, 2)))
void gemm_main(const u16* __restrict__ A,
               const u16* __restrict__ W,
               uint2* __restrict__ Bl) {
  __shared__ __align__(16) u16 lds[65536];   // 128 KiB

  const int tid = threadIdx.x;
  const int lane = tid & 63, wave = tid >> 6;
  const int wg_m = wave >> 2;
  const int lr = lane & 15;

  // bijective XCD swizzle (nwg=512, 512%8==0)
  int bid = blockIdx.x;
  int swz = (bid & 7) * 64 + (bid >> 3);
  const int bn0 = (swz & 15) * 256;
  const int bm0 = (swz >> 4) * 256;

  // per-lane staging constants
  const int row_c = tid >> 3;
  const int xslot = ((tid & 7) ^ (row_c & 7)) << 3;
  const int gK0 = row_c * IN_F + xslot;
  const int gK1 = gK0 + 64 * IN_F;
  const int ldst0 = (tid & ~63) * 16;

  // per-lane frag-read constants
  const int lb0 = (lr << 7) | ((((lane >> 4)) ^ (lr & 7)) << 4);
  const int lb1 = (lr << 7) | (((4 | (lane >> 4)) ^ (lr & 7)) << 4);

  const u16* baseA0 = A + (size_t)bm0 * IN_F;
  const u16* baseA1 = A + (size_t)(bm0 + 128) * IN_F;
  const u16* baseW0 = W + (size_t)bn0 * IN_F;
  const u16* baseW1 = W + (size_t)(bn0 + 128) * IN_F;

  const int wg_n = wave & 3;
  const int b_row0 = (wg_n & 1) * 64;
  const char* pA0 = LAB(0, wg_m);
  const char* pA1 = LAB(1, wg_m);
  const char* pB0 = LBB(0, wg_n >> 1) + b_row0 * 128;
  const char* pB1 = LBB(1, wg_n >> 1) + b_row0 * 128;

  f32x4 acc[8][4];
#pragma unroll
  for (int m = 0; m < 8; ++m)
#pragma unroll
    for (int n = 0; n < 4; ++n)
#pragma unroll
      for (int v = 0; v < 4; ++v) acc[m][n][v] = 0.f;

  // ---- prologue: kt0 -> buf0 (B0,B1,A0,A1), kt1.B -> buf1 ----
  STG_K(baseW0, LBB(0, 0));
  STG_K(baseW1, LBB(0, 1));
  STG_K(baseA0, LAB(0, 0));
  STG_K(baseA1, LAB(0, 1));
  STG_K(baseW0 + 64, LBB(1, 0));
  STG_K(baseW1 + 64, LBB(1, 1));
  asm volatile("s_waitcnt vmcnt(4)" ::: "memory");
  __builtin_amdgcn_s_barrier();

  bf16x8 af[4][2];
  bf16x8 bfr[2][2][2];

  for (int u = 0; u < 31; ++u) {
    const int c1k = (2 * u + 1) * 64;
    const int n0k = (2 * u + 2) * 64;
    const int n1k = (2 * u + 3) * 64;

    // ---- P1: quad(0,0) on buf0 ----
#pragma unroll
    for (int mf = 0; mf < 4; ++mf) {
      af[mf][0] = LDF(pA0, mf * 2048, lb0);
      af[mf][1] = LDF(pA0, mf * 2048, lb1);
    }
#pragma unroll
    for (int nf = 0; nf < 2; ++nf) {
      bfr[0][nf][0] = LDF(pB0, nf * 2048, lb0);
      bfr[0][nf][1] = LDF(pB0, nf * 2048, lb1);
    }
    STG_K(baseA0 + c1k, LAB(1, 0));
    PHASE_MID; MFMA_QUAD(0, 0); PHASE_END;

    // ---- P2: quad(0,1) ----
#pragma unroll
    for (int nf = 0; nf < 2; ++nf) {
      bfr[1][nf][0] = LDF(pB0, 4096 + nf * 2048, lb0);
      bfr[1][nf][1] = LDF(pB0, 4096 + nf * 2048, lb1);
    }
    STG_K(baseA1 + c1k, LAB(1, 1));
    PHASE_MID; MFMA_QUAD(0, 1); PHASE_END;

    // ---- P3: quad(1,1) ----
#pragma unroll
    for (int mf = 0; mf < 4; ++mf) {
      af[mf][0] = LDF(pA0, 8192 + mf * 2048, lb0);
      af[mf][1] = LDF(pA0, 8192 + mf * 2048, lb1);
    }
    STG_K(baseW0 + n0k, LBB(0, 0));
    PHASE_MID; MFMA_QUAD(1, 1); PHASE_END;

    // ---- P4: quad(1,0) ----
    STG_K(baseW1 + n0k, LBB(0, 1));
    PHASE_MID; MFMA_QUAD(1, 0); PHASE_END_VM;

    // ---- P5: quad(0,0) on buf1 ----
#pragma unroll
    for (int mf = 0; mf < 4; ++mf) {
      af[mf][0] = LDF(pA1, mf * 2048, lb0);
      af[mf][1] = LDF(pA1, mf * 2048, lb1);
    }
#pragma unroll
    for (int nf = 0; nf < 2; ++nf) {
      bfr[0][nf][0] = LDF(pB1, nf * 2048, lb0);
      bfr[0][nf][1] = LDF(pB1, nf * 2048, lb1);
    }
    STG_K(baseA0 + n0k, LAB(0, 0));
    PHASE_MID; MFMA_QUAD(0, 0); PHASE_END;

    // ---- P6: quad(0,1) ----
#pragma unroll
    for (int nf = 0; nf < 2; ++nf) {
      bfr[1][nf][0] = LDF(pB1, 4096 + nf * 2048, lb0);
      bfr[1][nf][1] = LDF(pB1, 4096 + nf * 2048, lb1);
    }
    STG_K(baseA1 + n0k, LAB(0, 1));
    PHASE_MID; MFMA_QUAD(0, 1); PHASE_END;

    // ---- P7: quad(1,1) ----
#pragma unroll
    for (int mf = 0; mf < 4; ++mf) {
      af[mf][0] = LDF(pA1, 8192 + mf * 2048, lb0);
      af[mf][1] = LDF(pA1, 8192 + mf * 2048, lb1);
    }
    STG_K(baseW0 + n1k, LBB(1, 0));
    PHASE_MID; MFMA_QUAD(1, 1); PHASE_END;

    // ---- P8: quad(1,0) ----
    STG_K(baseW1 + n1k, LBB(1, 1));
    PHASE_MID; MFMA_QUAD(1, 0); PHASE_END_VM;
  }

  // ---- peeled tail (u=31): only buf1.A (kt63) staged; no next-tile loads ----
  {
    const int c1k = 63 * 64;

    // P1
#pragma unroll
    for (int mf = 0; mf < 4; ++mf) {
      af[mf][0] = LDF(pA0, mf * 2048, lb0);
      af[mf][1] = LDF(pA0, mf * 2048, lb1);
    }
#pragma unroll
    for (int nf = 0; nf < 2; ++nf) {
      bfr[0][nf][0] = LDF(pB0, nf * 2048, lb0);
      bfr[0][nf][1] = LDF(pB0, nf * 2048, lb1);
    }
    STG_K(baseA0 + c1k, LAB(1, 0));
    PHASE_MID; MFMA_QUAD(0, 0); PHASE_END;

    // P2
#pragma unroll
    for (int nf = 0; nf < 2; ++nf) {
      bfr[1][nf][0] = LDF(pB0, 4096 + nf * 2048, lb0);
      bfr[1][nf][1] = LDF(pB0, 4096 + nf * 2048, lb1);
    }
    STG_K(baseA1 + c1k, LAB(1, 1));
    PHASE_MID; MFMA_QUAD(0, 1); PHASE_END;

    // P3
#pragma unroll
    for (int mf = 0; mf < 4; ++mf) {
      af[mf][0] = LDF(pA0, 8192 + mf * 2048, lb0);
      af[mf][1] = LDF(pA0, 8192 + mf * 2048, lb1);
    }
    PHASE_MID; MFMA_QUAD(1, 1); PHASE_END;

    // P4: only 4 loads outstanding -> must drain fully before buf1.A reads
    PHASE_MID; MFMA_QUAD(1, 0); PHASE_END_VM0;

    // P5
#pragma unroll
    for (int mf = 0; mf < 4; ++mf) {
      af[mf][0] = LDF(pA1, mf * 2048, lb0);
      af[mf][1] = LDF(pA1, mf * 2048, lb1);
    }
#pragma unroll
    for (int nf = 0; nf < 2; ++nf) {
      bfr[0][nf][0] = LDF(pB1, nf * 2048, lb0);
      bfr[0][nf][1] = LDF(pB1, nf * 2048, lb1);
    }
    PHASE_MID; MFMA_QUAD(0, 0); PHASE_END;

    // P6
#pragma unroll
    for (int nf = 0; nf < 2; ++nf) {
      bfr[1][nf][0] = LDF(pB1, 4096 + nf * 2048, lb0);
      bfr[1][nf][1] = LDF(pB1, 4096 + nf * 2048, lb1);
    }
    PHASE_MID; MFMA_QUAD(0, 1); PHASE_END;

    // P7
#pragma unroll
    for (int mf = 0; mf < 4; ++mf) {
      af[mf][0] = LDF(pA1, 8192 + mf * 2048, lb0);
      af[mf][1] = LDF(pA1, 8192 + mf * 2048, lb1);
    }
    PHASE_MID; MFMA_QUAD(1, 1); PHASE_END;

    // P8
    PHASE_MID; MFMA_QUAD(1, 0); PHASE_END;
  }

  // ---- store baseline: packed bf16, native per-thread layout ----
  const size_t tbase = ((size_t)bid * 8 + wave) * 32;
#pragma unroll
  for (int mf = 0; mf < 8; ++mf)
#pragma unroll
    for (int nf = 0; nf < 4; ++nf) {
      f32x4 a = acc[mf][nf];
      uint2 pk;
      pk.x = (u32)f2bf(a[0]) | ((u32)f2bf(a[1]) << 16);
      pk.y = (u32)f2bf(a[2]) | ((u32)f2bf(a[3]) << 16);
      Bl[(tbase + mf * 4 + nf) * 64 + lane] = pk;
    }
}

// ---------------- lr_apply: out = (H·L2a + bias) + (H·L2m + scale) * baseline ----------------
// Same geometry/swizzle as gemm_main; reads baseline in native layout.

__global__ __launch_bounds__(512)
void lr_apply(const uint2* __restrict__ Bl,
              const u16* __restrict__ H,
              const u16* __restrict__ L2,
              const float* __restrict__ scale,
              const float* __restrict__ bias,
              float* __restrict__ out) {
  __shared__ __align__(16) u16 lds[65536];   // 128 KiB

  const int tid = threadIdx.x;
  const int lane = tid & 63, wave = tid >> 6;
  const int wg_m = wave >> 2, wg_n = wave & 3;
  const int lr = lane & 15;

  int bid = blockIdx.x;
  int swz = (bid & 7) * 64 + (bid >> 3);
  const int bn0 = (swz & 15) * 256;
  const int bm0 = (swz >> 4) * 256;

  const int row_c = tid >> 3;
  const int xslot = ((tid & 7) ^ (row_c & 7)) << 3;
  const int gL0 = row_c * LRANK + xslot;
  const int gL1 = gL0 + 64 * LRANK;
  const int ldst0 = (tid & ~63) * 16;

  const int lb0 = (lr << 7) | ((((lane >> 4)) ^ (lr & 7)) << 4);
  const int lb1 = (lr << 7) | (((4 | (lane >> 4)) ^ (lr & 7)) << 4);

  float scl[4], bs_[4];
#pragma unroll
  for (int nf = 0; nf < 4; ++nf) {
    int cg = bn0 + wg_n * 64 + nf * 16 + lr;
    scl[nf] = scale[cg];
    bs_[nf] = bias[cg];
  }

  // stage H (4 halves) + L2m (4 halves):
  // H(s,h) = s*32768 + h*16384 ; L2(s,h) = 65536 + s*32768 + h*16384
  {
    const u16* baseH0 = H + (size_t)bm0 * LRANK;
    const u16* baseH1 = H + (size_t)(bm0 + 128) * LRANK;
    const u16* baseL0 = L2 + (size_t)bn0 * LRANK;
    const u16* baseL1 = L2 + (size_t)(bn0 + 128) * LRANK;
    STG_L(baseH0,      (char*)lds + 0);
    STG_L(baseH1,      (char*)lds + 16384);
    STG_L(baseH0 + 64, (char*)lds + 32768);
    STG_L(baseH1 + 64, (char*)lds + 49152);
    STG_L(baseL0,      (char*)lds + 65536);
    STG_L(baseL1,      (char*)lds + 81920);
    STG_L(baseL0 + 64, (char*)lds + 98304);
    STG_L(baseL1 + 64, (char*)lds + 114688);
  }
  __syncthreads();

  const char* pH = (char*)lds + wg_m * 16384;
  const char* pL = (char*)lds + 65536 + (wg_n >> 1) * 16384 + (wg_n & 1) * 8192;

  // full multiplicative accumulator
  f32x4 maccM[8][4];
#pragma unroll
  for (int m = 0; m < 8; ++m)
#pragma unroll
    for (int n = 0; n < 4; ++n)
#pragma unroll
      for (int v = 0; v < 4; ++v) maccM[m][n][v] = 0.f;

#pragma unroll
  for (int kc = 0; kc < 4; ++kc) {
    const int sb = (kc >> 1) * 32768;
    const int lb = (kc & 1) ? lb1 : lb0;
    bf16x8 lf[4];
#pragma unroll
    for (int nf = 0; nf < 4; ++nf)
      lf[nf] = LDF(pL + sb, nf * 2048, lb);
#pragma unroll
    for (int mf = 0; mf < 8; ++mf) {
      bf16x8 hf = LDF(pH + sb, mf * 2048, lb);
#pragma unroll
      for (int nf = 0; nf < 4; ++nf)
        maccM[mf][nf] = __builtin_amdgcn_mfma_f32_16x16x32_bf16(hf, lf[nf], maccM[mf][nf], 0, 0, 0);
    }
  }

  // restage L2 additive rows over the L2m region
  __syncthreads();
  {
    const u16* baseL0 = L2 + (size_t)(OUT_F + bn0) * LRANK;
    const u16* baseL1 = L2 + (size_t)(OUT_F + bn0 + 128) * LRANK;
    STG_L(baseL0,      (char*)lds + 65536);
    STG_L(baseL1,      (char*)lds + 81920);
    STG_L(baseL0 + 64, (char*)lds + 98304);
    STG_L(baseL1 + 64, (char*)lds + 114688);
  }
  __syncthreads();

  // additive pass chunked by m-quarter, immediate apply + store
  const size_t tbase = ((size_t)bid * 8 + wave) * 32;
#pragma unroll
  for (int mq = 0; mq < 4; ++mq) {
    f32x4 maccA[2][4];
#pragma unroll
    for (int m = 0; m < 2; ++m)
#pragma unroll
      for (int n = 0; n < 4; ++n)
#pragma unroll
        for (int v = 0; v < 4; ++v) maccA[m][n][v] = 0.f;

#pragma unroll
    for (int kc = 0; kc < 4; ++kc) {
      const int sb = (kc >> 1) * 32768;
      const int lb = (kc & 1) ? lb1 : lb0;
      bf16x8 lf[4];
#pragma unroll
      for (int nf = 0; nf < 4; ++nf)
        lf[nf] = LDF(pL + sb, nf * 2048, lb);
#pragma unroll
      for (int mf = 0; mf < 2; ++mf) {
        bf16x8 hf = LDF(pH + sb, (mq * 2 + mf) * 2048, lb);
#pragma unroll
        for (int nf = 0; nf < 4; ++nf)
          maccA[mf][nf] = __builtin_amdgcn_mfma_f32_16x16x32_bf16(hf, lf[nf], maccA[mf][nf], 0, 0, 0);
      }
    }

#pragma unroll
    for (int mf = 0; mf < 2; ++mf)
#pragma unroll
      for (int nf = 0; nf < 4; ++nf) {
        int m8 = mq * 2 + mf;
        uint2 pk = Bl[(tbase + m8 * 4 + nf) * 64 + lane];
        float b0 = bf2f((u16)(pk.x & 0xffff));
        float b1 = bf2f((u16)(pk.x >> 16));
        float b2 = bf2f((u16)(pk.y & 0xffff));
        float b3 = bf2f((u16)(pk.y >> 16));
        int rg = bm0 + wg_m * 128 + m8 * 16 + (lane >> 4) * 4;
        int cg = bn0 + wg_n * 64 + nf * 16 + lr;
        float* op = out + (size_t)rg * OUT_F + cg;
        op[0 * OUT_F] = (maccA[mf][nf][0] + bs_[nf]) + (maccM[m8][nf][0] + scl[nf]) * b0;
        op[1 * OUT_F] = (maccA[mf][nf][1] + bs_[nf]) + (maccM[m8][nf][1] + scl[nf]) * b1;
        op[2 * OUT_F] = (maccA[mf][nf][2] + bs_[nf]) + (maccM[m8][nf][2] + scl[nf]) * b2;
        op[3 * OUT_F] = (maccA[mf][nf][3] + bs_[nf]) + (maccM[m8][nf][3] + scl[nf]) * b3;
      }
  }
}

// ---------------- launch ----------------

extern "C" void kernel_launch(void* const* d_in, const int* in_sizes, int n_in,
                              void* d_out, int out_size, void* d_ws, size_t ws_size,
                              hipStream_t stream) {
  const float* input = (const float*)d_in[0];
  const int*   zm    = (const int*)d_in[1];
  const float* cb    = (const float*)d_in[2];
  const float* l1    = (const float*)d_in[3];
  const float* l2    = (const float*)d_in[4];
  const float* gs    = (const float*)d_in[5];
  const float* gb    = (const float*)d_in[6];
  const float* scale = (const float*)d_in[7];
  const float* bias  = (const float*)d_in[8];
  float* out = (float*)d_out;

  const size_t OFF_A  = 0;                                        // 64 MiB
  const size_t OFF_W  = OFF_A + (size_t)NTOK * IN_F * 2;          // 32 MiB
  const size_t OFF_L1 = OFF_W + (size_t)OUT_F * IN_F * 2;         // 1 MiB
  const size_t OFF_L2 = OFF_L1 + (size_t)LRANK * IN_F * 2;        // 2 MiB
  const size_t OFF_H  = OFF_L2 + (size_t)2 * OUT_F * LRANK * 2;   // 2 MiB
  const size_t OFF_BL = OFF_H + (size_t)NTOK * LRANK * 2;         // 64 MiB (bf16 packed)
  const size_t NEED   = OFF_BL + (size_t)NTOK * OUT_F * 2;
  if (ws_size < NEED) return;

  char* ws = (char*)d_ws;
  u16* A    = (u16*)(ws + OFF_A);
  u16* W    = (u16*)(ws + OFF_W);
  u16* L1b  = (u16*)(ws + OFF_L1);
  u16* L2b  = (u16*)(ws + OFF_L2);
  u16* H    = (u16*)(ws + OFF_H);
  uint2* Bl = (uint2*)(ws + OFF_BL);
  // Hp (16 MiB f32 partials) overlays the Bl region: Hp is dead before
  // gemm_main writes Bl (serial stream), so no conflict.
  float* Hp = (float*)(ws + OFF_BL);

  cvt_bf16_2_kernel<<<((LRANK * IN_F + 2 * OUT_F * LRANK) / 4 + 255) / 256, 256, 0, stream>>>(
      l1, L1b, LRANK * IN_F / 4, l2, L2b, 2 * OUT_F * LRANK / 4);
  dequant_kernel<<<(OUT_F * IN_F / 4) / 256, 256, 0, stream>>>(zm, cb, gs, gb, W);

  hid_part<<<4 * (NTOK / 128), 256, 0, stream>>>(input, A, L1b, Hp);
  hid_reduce<<<(NTOK * LRANK / 4) / 256, 256, 0, stream>>>(Hp, H);

  gemm_main<<<(NTOK / 256) * (OUT_F / 256), 512, 0, stream>>>(A, W, Bl);

  lr_apply<<<(NTOK / 256) * (OUT_F / 256), 512, 0, stream>>>(Bl, H, L2b, scale, bias, out);
}

// Round 10
// 342.695 us; speedup vs baseline: 2.0495x; 1.0939x over previous
//
#include <hip/hip_runtime.h>
#include <hip/hip_bf16.h>

#define IN_F   4096
#define OUT_F  4096
#define NTOK   8192
#define LRANK  128

typedef unsigned short u16;
typedef unsigned int u32;
typedef __attribute__((ext_vector_type(8))) __bf16 bf16x8;
typedef __attribute__((ext_vector_type(4))) float f32x4;

__device__ __forceinline__ u16 f2bf(float f) {
  union { float f; unsigned u; } a; a.f = f;
  return (u16)((a.u + 0x7fffu + ((a.u >> 16) & 1u)) >> 16);
}
__device__ __forceinline__ float bf2f(u16 b) {
  union { unsigned u; float f; } a; a.u = (u32)b << 16;
  return a.f;
}

// async global->LDS, 16B per lane. LDS dest is wave-uniform base + lane*16.
__device__ __forceinline__ void async_ld16(const void* g, void* l) {
  __builtin_amdgcn_global_load_lds(
      (__attribute__((address_space(1))) void*)(unsigned long long)g,
      (__attribute__((address_space(3))) void*)(unsigned int)(unsigned long long)l,
      16, 0, 0);
}

// ---------------- prep kernels ----------------

// merged small converts (L1, L2)
__global__ void cvt_bf16_2_kernel(const float* __restrict__ s1, u16* __restrict__ d1, int n1,
                                  const float* __restrict__ s2, u16* __restrict__ d2, int n2) {
  int i = blockIdx.x * blockDim.x + threadIdx.x;
  const float* s; u16* d; int j;
  if (i < n1) { s = s1; d = d1; j = i; }
  else if (i < n1 + n2) { s = s2; d = d2; j = i - n1; }
  else return;
  float4 v = ((const float4*)s)[j];
  ushort4 o;
  o.x = f2bf(v.x); o.y = f2bf(v.y); o.z = f2bf(v.z); o.w = f2bf(v.w);
  ((ushort4*)d)[j] = o;
}

__global__ void dequant_kernel(const int* __restrict__ zm, const float* __restrict__ cb,
                               const float* __restrict__ gs, const float* __restrict__ gb,
                               u16* __restrict__ W) {
  int idx = blockIdx.x * blockDim.x + threadIdx.x;   // one thread per 4 weights
  if (idx >= OUT_F * IN_F / 4) return;
  int o = idx >> 10;
  int i = (idx & 1023) << 2;
  int row = ((o >> 6) << 6) + (i >> 6);
  const int* zp = zm + ((size_t)row << 12) + ((o & 63) << 6) + (i & 63);
  int4 z = *(const int4*)zp;
  const float* cr = cb + ((size_t)row << 8);
  int g = (o >> 3) * (IN_F / 8) + (i >> 3);
  float s = gs[g], b = gb[g];
  ushort4 w;
  w.x = f2bf(b + cr[z.x] * s);
  w.y = f2bf(b + cr[z.y] * s);
  w.z = f2bf(b + cr[z.z] * s);
  w.w = f2bf(b + cr[z.w] * s);
  *(ushort4*)(W + (size_t)idx * 4) = w;
}

// ---------------- hid GEMM, K-split x8, fused input conversion, prefetch ----------------
// Block (mt, kc): token rows mt*128..+128, K cols kc*512..+512.
// f32 input loaded one K-tile AHEAD of the MFMA consuming it (latency hiding).

__device__ __forceinline__ void stage_tile_128x32(const u16* __restrict__ g, int stride,
                                                  int row0, int col0,
                                                  u16* lbase, int wave, int lane) {
#pragma unroll
  for (int p = 0; p < 2; ++p) {
    int li_base = wave * 64 + p * 256;
    int li = li_base + lane;
    const u16* gaddr = g + (size_t)(row0 + (li >> 2)) * stride + col0 + ((li & 3) << 3);
    async_ld16(gaddr, lbase + li_base * 8);
  }
}

__global__ __launch_bounds__(256) void hid_part(const float* __restrict__ input,
                                                u16* __restrict__ A,
                                                const u16* __restrict__ L1,
                                                float* __restrict__ Hp) {
  __shared__ __align__(16) u16 lds[2 * 128 * 32];
  u16* ldsA = lds;
  u16* ldsB = lds + 128 * 32;

  int tid = threadIdx.x;
  int wave = tid >> 6, lane = tid & 63;
  int kc  = blockIdx.x & 7;
  int bm0 = (blockIdx.x >> 3) * 128;
  int kbase = kc * 512;
  int wr = (wave >> 1) * 64, wc = (wave & 1) * 64;
  int lrow = lane & 15, lk = (lane >> 4) * 8;

  // conversion coords: 2 threads per row, 16 cols each
  const int crow = tid >> 1;
  const int c16  = (tid & 1) * 16;

  f32x4 acc[4][4];
#pragma unroll
  for (int m = 0; m < 4; ++m)
#pragma unroll
    for (int n = 0; n < 4; ++n)
#pragma unroll
      for (int v = 0; v < 4; ++v) acc[m][n][v] = 0.f;

  const float* ip = input + (size_t)(bm0 + crow) * IN_F + kbase + c16;
  float4 v0 = ((const float4*)ip)[0];
  float4 v1 = ((const float4*)ip)[1];
  float4 v2 = ((const float4*)ip)[2];
  float4 v3 = ((const float4*)ip)[3];

  for (int kt = 0; kt < 16; ++kt) {
    int k0 = kbase + kt * 32;

    // L1 tile via async gload_lds (bf16 already)
    stage_tile_128x32(L1, IN_F, 0, k0, ldsB, wave, lane);

    // convert the prefetched f32 chunk -> bf16 -> LDS + global A side-write
    {
      ushort4 o0, o1, o2, o3;
      o0.x = f2bf(v0.x); o0.y = f2bf(v0.y); o0.z = f2bf(v0.z); o0.w = f2bf(v0.w);
      o1.x = f2bf(v1.x); o1.y = f2bf(v1.y); o1.z = f2bf(v1.z); o1.w = f2bf(v1.w);
      o2.x = f2bf(v2.x); o2.y = f2bf(v2.y); o2.z = f2bf(v2.z); o2.w = f2bf(v2.w);
      o3.x = f2bf(v3.x); o3.y = f2bf(v3.y); o3.z = f2bf(v3.z); o3.w = f2bf(v3.w);
      u16* lp = &ldsA[crow * 32 + c16];
      ((ushort4*)lp)[0] = o0; ((ushort4*)lp)[1] = o1;
      ((ushort4*)lp)[2] = o2; ((ushort4*)lp)[3] = o3;
      u16* gp = A + (size_t)(bm0 + crow) * IN_F + k0 + c16;
      ((ushort4*)gp)[0] = o0; ((ushort4*)gp)[1] = o1;
      ((ushort4*)gp)[2] = o2; ((ushort4*)gp)[3] = o3;
    }

    // issue next chunk's loads (they fly during the MFMA below)
    if (kt < 15) {
      ip += 32;
      v0 = ((const float4*)ip)[0];
      v1 = ((const float4*)ip)[1];
      v2 = ((const float4*)ip)[2];
      v3 = ((const float4*)ip)[3];
    }
    __syncthreads();

    bf16x8 af[4], bfr[4];
#pragma unroll
    for (int m = 0; m < 4; ++m)
      af[m] = *(const bf16x8*)&ldsA[(wr + m * 16 + lrow) * 32 + lk];
#pragma unroll
    for (int n = 0; n < 4; ++n)
      bfr[n] = *(const bf16x8*)&ldsB[(wc + n * 16 + lrow) * 32 + lk];
#pragma unroll
    for (int m = 0; m < 4; ++m)
#pragma unroll
      for (int n = 0; n < 4; ++n)
        acc[m][n] = __builtin_amdgcn_mfma_f32_16x16x32_bf16(af[m], bfr[n], acc[m][n], 0, 0, 0);
    __syncthreads();
  }

  float* Hpk = Hp + (size_t)kc * NTOK * LRANK;
  int lrow4 = (lane >> 4) * 4;
#pragma unroll
  for (int m = 0; m < 4; ++m)
#pragma unroll
    for (int n = 0; n < 4; ++n)
#pragma unroll
      for (int v = 0; v < 4; ++v) {
        int rg = bm0 + wr + m * 16 + lrow4 + v;
        int cg = wc + n * 16 + lrow;
        Hpk[(size_t)rg * LRANK + cg] = acc[m][n][v];
      }
}

__global__ void hid_reduce(const float* __restrict__ Hp, u16* __restrict__ H) {
  int i = blockIdx.x * blockDim.x + threadIdx.x;   // one thread per 4 elems
  if (i >= NTOK * LRANK / 4) return;
  const size_t stride = (size_t)NTOK * LRANK;
  float4 a0 = ((const float4*)Hp)[i];
#pragma unroll
  for (int p = 1; p < 8; ++p) {
    float4 ap = ((const float4*)(Hp + p * stride))[i];
    a0.x += ap.x; a0.y += ap.y; a0.z += ap.z; a0.w += ap.w;
  }
  ushort4 o;
  o.x = f2bf(a0.x); o.y = f2bf(a0.y); o.z = f2bf(a0.z); o.w = f2bf(a0.w);
  ((ushort4*)H)[i] = o;
}

// ---------------- main GEMM: 256x256 tile, BK=64, 8-phase schedule ----------------
// K-loop identical to the verified round-6/7 kernel. FUSED low-rank epilogue:
// baseline packed to bf16 IN-REGISTER (pk, 64 regs), maccM/maccA computed in
// [2][4] chunks (32 regs) -> peak acc-class pressure stays far below 256.

#define MFMA_QUAD(mh, nh)                                                        \
  _Pragma("unroll") for (int mf = 0; mf < 4; ++mf)                               \
  _Pragma("unroll") for (int nf = 0; nf < 2; ++nf)                               \
  _Pragma("unroll") for (int ks = 0; ks < 2; ++ks)                               \
    acc[(mh)*4 + mf][(nh)*2 + nf] = __builtin_amdgcn_mfma_f32_16x16x32_bf16(     \
        af[mf][ks], bfr[nh][nf][ks], acc[(mh)*4 + mf][(nh)*2 + nf], 0, 0, 0);

#define PHASE_MID                                          \
  __builtin_amdgcn_s_barrier();                            \
  asm volatile("s_waitcnt lgkmcnt(0)" ::: "memory");       \
  __builtin_amdgcn_sched_barrier(0);                       \
  __builtin_amdgcn_s_setprio(1);

#define PHASE_END                                          \
  __builtin_amdgcn_s_setprio(0);                           \
  __builtin_amdgcn_s_barrier();

#define PHASE_END_VM                                       \
  __builtin_amdgcn_s_setprio(0);                           \
  asm volatile("s_waitcnt vmcnt(4)" ::: "memory");         \
  __builtin_amdgcn_s_barrier();

#define PHASE_END_VM0                                      \
  __builtin_amdgcn_s_setprio(0);                           \
  asm volatile("s_waitcnt vmcnt(0)" ::: "memory");         \
  __builtin_amdgcn_s_barrier();

// LDS regions (bytes): buf b at b*65536; A halves +0,+16384; B halves +32768,+49152
#define LAB(b, h) ((char*)lds + (b) * 65536 + (h) * 16384)
#define LBB(b, h) ((char*)lds + (b) * 65536 + 32768 + (h) * 16384)

#define STG_K(gbase, lreg) do {                               \
    async_ld16((gbase) + gK0, (lreg) + ldst0);                \
    async_ld16((gbase) + gK1, (lreg) + ldst0 + 8192); } while (0)
#define STG_L(gbase, lreg) do {                               \
    async_ld16((gbase) + gL0, (lreg) + ldst0);                \
    async_ld16((gbase) + gL1, (lreg) + ldst0 + 8192); } while (0)

#define LDF(p, byteoff, lb) (*(const bf16x8*)((p) + (byteoff) + (lb)))

__global__ __launch_bounds__(512)
__attribute__((amdgpu_waves_per_eu(2, 2)))
void gemm_main(const u16* __restrict__ A,
               const u16* __restrict__ W,
               const u16* __restrict__ H,
               const u16* __restrict__ L2,
               const float* __restrict__ scale,
               const float* __restrict__ bias,
               float* __restrict__ out) {
  __shared__ __align__(16) u16 lds[65536];   // 128 KiB

  const int tid = threadIdx.x;
  const int lane = tid & 63, wave = tid >> 6;
  const int wg_m = wave >> 2;
  const int lr = lane & 15;

  // bijective XCD swizzle (nwg=512, 512%8==0)
  int bid = blockIdx.x;
  int swz = (bid & 7) * 64 + (bid >> 3);
  const int bn0 = (swz & 15) * 256;
  const int bm0 = (swz >> 4) * 256;

  // per-lane staging constants
  const int row_c = tid >> 3;
  const int xslot = ((tid & 7) ^ (row_c & 7)) << 3;
  const int gK0 = row_c * IN_F + xslot;
  const int gK1 = gK0 + 64 * IN_F;
  const int ldst0 = (tid & ~63) * 16;

  // per-lane frag-read constants
  const int lb0 = (lr << 7) | ((((lane >> 4)) ^ (lr & 7)) << 4);
  const int lb1 = (lr << 7) | (((4 | (lane >> 4)) ^ (lr & 7)) << 4);

  const u16* baseA0 = A + (size_t)bm0 * IN_F;
  const u16* baseA1 = A + (size_t)(bm0 + 128) * IN_F;
  const u16* baseW0 = W + (size_t)bn0 * IN_F;
  const u16* baseW1 = W + (size_t)(bn0 + 128) * IN_F;

  const int wg_n = wave & 3;
  const int b_row0 = (wg_n & 1) * 64;
  const char* pA0 = LAB(0, wg_m);
  const char* pA1 = LAB(1, wg_m);
  const char* pB0 = LBB(0, wg_n >> 1) + b_row0 * 128;
  const char* pB1 = LBB(1, wg_n >> 1) + b_row0 * 128;

  f32x4 acc[8][4];
#pragma unroll
  for (int m = 0; m < 8; ++m)
#pragma unroll
    for (int n = 0; n < 4; ++n)
#pragma unroll
      for (int v = 0; v < 4; ++v) acc[m][n][v] = 0.f;

  // ---- prologue: kt0 -> buf0 (B0,B1,A0,A1), kt1.B -> buf1 ----
  STG_K(baseW0, LBB(0, 0));
  STG_K(baseW1, LBB(0, 1));
  STG_K(baseA0, LAB(0, 0));
  STG_K(baseA1, LAB(0, 1));
  STG_K(baseW0 + 64, LBB(1, 0));
  STG_K(baseW1 + 64, LBB(1, 1));
  asm volatile("s_waitcnt vmcnt(4)" ::: "memory");
  __builtin_amdgcn_s_barrier();

  bf16x8 af[4][2];
  bf16x8 bfr[2][2][2];

  for (int u = 0; u < 31; ++u) {
    const int c1k = (2 * u + 1) * 64;
    const int n0k = (2 * u + 2) * 64;
    const int n1k = (2 * u + 3) * 64;

    // ---- P1: quad(0,0) on buf0 ----
#pragma unroll
    for (int mf = 0; mf < 4; ++mf) {
      af[mf][0] = LDF(pA0, mf * 2048, lb0);
      af[mf][1] = LDF(pA0, mf * 2048, lb1);
    }
#pragma unroll
    for (int nf = 0; nf < 2; ++nf) {
      bfr[0][nf][0] = LDF(pB0, nf * 2048, lb0);
      bfr[0][nf][1] = LDF(pB0, nf * 2048, lb1);
    }
    STG_K(baseA0 + c1k, LAB(1, 0));
    PHASE_MID; MFMA_QUAD(0, 0); PHASE_END;

    // ---- P2: quad(0,1) ----
#pragma unroll
    for (int nf = 0; nf < 2; ++nf) {
      bfr[1][nf][0] = LDF(pB0, 4096 + nf * 2048, lb0);
      bfr[1][nf][1] = LDF(pB0, 4096 + nf * 2048, lb1);
    }
    STG_K(baseA1 + c1k, LAB(1, 1));
    PHASE_MID; MFMA_QUAD(0, 1); PHASE_END;

    // ---- P3: quad(1,1) ----
#pragma unroll
    for (int mf = 0; mf < 4; ++mf) {
      af[mf][0] = LDF(pA0, 8192 + mf * 2048, lb0);
      af[mf][1] = LDF(pA0, 8192 + mf * 2048, lb1);
    }
    STG_K(baseW0 + n0k, LBB(0, 0));
    PHASE_MID; MFMA_QUAD(1, 1); PHASE_END;

    // ---- P4: quad(1,0) ----
    STG_K(baseW1 + n0k, LBB(0, 1));
    PHASE_MID; MFMA_QUAD(1, 0); PHASE_END_VM;

    // ---- P5: quad(0,0) on buf1 ----
#pragma unroll
    for (int mf = 0; mf < 4; ++mf) {
      af[mf][0] = LDF(pA1, mf * 2048, lb0);
      af[mf][1] = LDF(pA1, mf * 2048, lb1);
    }
#pragma unroll
    for (int nf = 0; nf < 2; ++nf) {
      bfr[0][nf][0] = LDF(pB1, nf * 2048, lb0);
      bfr[0][nf][1] = LDF(pB1, nf * 2048, lb1);
    }
    STG_K(baseA0 + n0k, LAB(0, 0));
    PHASE_MID; MFMA_QUAD(0, 0); PHASE_END;

    // ---- P6: quad(0,1) ----
#pragma unroll
    for (int nf = 0; nf < 2; ++nf) {
      bfr[1][nf][0] = LDF(pB1, 4096 + nf * 2048, lb0);
      bfr[1][nf][1] = LDF(pB1, 4096 + nf * 2048, lb1);
    }
    STG_K(baseA1 + n0k, LAB(0, 1));
    PHASE_MID; MFMA_QUAD(0, 1); PHASE_END;

    // ---- P7: quad(1,1) ----
#pragma unroll
    for (int mf = 0; mf < 4; ++mf) {
      af[mf][0] = LDF(pA1, 8192 + mf * 2048, lb0);
      af[mf][1] = LDF(pA1, 8192 + mf * 2048, lb1);
    }
    STG_K(baseW0 + n1k, LBB(1, 0));
    PHASE_MID; MFMA_QUAD(1, 1); PHASE_END;

    // ---- P8: quad(1,0) ----
    STG_K(baseW1 + n1k, LBB(1, 1));
    PHASE_MID; MFMA_QUAD(1, 0); PHASE_END_VM;
  }

  // ---- peeled tail (u=31): only buf1.A (kt63) staged; no next-tile loads ----
  {
    const int c1k = 63 * 64;

    // P1
#pragma unroll
    for (int mf = 0; mf < 4; ++mf) {
      af[mf][0] = LDF(pA0, mf * 2048, lb0);
      af[mf][1] = LDF(pA0, mf * 2048, lb1);
    }
#pragma unroll
    for (int nf = 0; nf < 2; ++nf) {
      bfr[0][nf][0] = LDF(pB0, nf * 2048, lb0);
      bfr[0][nf][1] = LDF(pB0, nf * 2048, lb1);
    }
    STG_K(baseA0 + c1k, LAB(1, 0));
    PHASE_MID; MFMA_QUAD(0, 0); PHASE_END;

    // P2
#pragma unroll
    for (int nf = 0; nf < 2; ++nf) {
      bfr[1][nf][0] = LDF(pB0, 4096 + nf * 2048, lb0);
      bfr[1][nf][1] = LDF(pB0, 4096 + nf * 2048, lb1);
    }
    STG_K(baseA1 + c1k, LAB(1, 1));
    PHASE_MID; MFMA_QUAD(0, 1); PHASE_END;

    // P3
#pragma unroll
    for (int mf = 0; mf < 4; ++mf) {
      af[mf][0] = LDF(pA0, 8192 + mf * 2048, lb0);
      af[mf][1] = LDF(pA0, 8192 + mf * 2048, lb1);
    }
    PHASE_MID; MFMA_QUAD(1, 1); PHASE_END;

    // P4: only 4 loads outstanding -> drain fully before buf1.A reads
    PHASE_MID; MFMA_QUAD(1, 0); PHASE_END_VM0;

    // P5
#pragma unroll
    for (int mf = 0; mf < 4; ++mf) {
      af[mf][0] = LDF(pA1, mf * 2048, lb0);
      af[mf][1] = LDF(pA1, mf * 2048, lb1);
    }
#pragma unroll
    for (int nf = 0; nf < 2; ++nf) {
      bfr[0][nf][0] = LDF(pB1, nf * 2048, lb0);
      bfr[0][nf][1] = LDF(pB1, nf * 2048, lb1);
    }
    PHASE_MID; MFMA_QUAD(0, 0); PHASE_END;

    // P6
#pragma unroll
    for (int nf = 0; nf < 2; ++nf) {
      bfr[1][nf][0] = LDF(pB1, 4096 + nf * 2048, lb0);
      bfr[1][nf][1] = LDF(pB1, 4096 + nf * 2048, lb1);
    }
    PHASE_MID; MFMA_QUAD(0, 1); PHASE_END;

    // P7
#pragma unroll
    for (int mf = 0; mf < 4; ++mf) {
      af[mf][0] = LDF(pA1, 8192 + mf * 2048, lb0);
      af[mf][1] = LDF(pA1, 8192 + mf * 2048, lb1);
    }
    PHASE_MID; MFMA_QUAD(1, 1); PHASE_END;

    // P8
    PHASE_MID; MFMA_QUAD(1, 0); PHASE_END;
  }

  // ---- pack baseline to bf16 in-register: acc(128 regs) -> pk(64 regs) ----
  uint2 pk[8][4];
#pragma unroll
  for (int mf = 0; mf < 8; ++mf)
#pragma unroll
    for (int nf = 0; nf < 4; ++nf) {
      pk[mf][nf].x = (u32)f2bf(acc[mf][nf][0]) | ((u32)f2bf(acc[mf][nf][1]) << 16);
      pk[mf][nf].y = (u32)f2bf(acc[mf][nf][2]) | ((u32)f2bf(acc[mf][nf][3]) << 16);
    }

  // ---- fused low-rank epilogue ----
  float scl[4], bs_[4];
#pragma unroll
  for (int nf = 0; nf < 4; ++nf) {
    int cg = bn0 + wg_n * 64 + nf * 16 + lr;
    scl[nf] = scale[cg];
    bs_[nf] = bias[cg];
  }

  const int gL0 = row_c * LRANK + xslot;
  const int gL1 = gL0 + 64 * LRANK;

  // drain K-loop stages, then stage H (64KB) + L2m (64KB):
  // H(s,h) = s*32768 + h*16384 ; L2(s,h) = 65536 + s*32768 + h*16384
  asm volatile("s_waitcnt vmcnt(0)" ::: "memory");
  __builtin_amdgcn_s_barrier();
  {
    const u16* baseH0 = H + (size_t)bm0 * LRANK;
    const u16* baseH1 = H + (size_t)(bm0 + 128) * LRANK;
    const u16* baseL0 = L2 + (size_t)bn0 * LRANK;
    const u16* baseL1 = L2 + (size_t)(bn0 + 128) * LRANK;
    STG_L(baseH0,      (char*)lds + 0);
    STG_L(baseH1,      (char*)lds + 16384);
    STG_L(baseH0 + 64, (char*)lds + 32768);
    STG_L(baseH1 + 64, (char*)lds + 49152);
    STG_L(baseL0,      (char*)lds + 65536);
    STG_L(baseL1,      (char*)lds + 81920);
    STG_L(baseL0 + 64, (char*)lds + 98304);
    STG_L(baseL1 + 64, (char*)lds + 114688);
  }
  asm volatile("s_waitcnt vmcnt(0)" ::: "memory");
  __builtin_amdgcn_s_barrier();

  const char* pH = (char*)lds + wg_m * 16384;
  const char* pL = (char*)lds + 65536 + (wg_n >> 1) * 16384 + (wg_n & 1) * 8192;

  // multiplicative pass, [2][4] chunks: pk <- pack((maccM+scale)*unpack(pk))
#pragma unroll
  for (int mq = 0; mq < 4; ++mq) {
    f32x4 macc[2][4];
#pragma unroll
    for (int m = 0; m < 2; ++m)
#pragma unroll
      for (int n = 0; n < 4; ++n)
#pragma unroll
        for (int v = 0; v < 4; ++v) macc[m][n][v] = 0.f;
#pragma unroll
    for (int kc = 0; kc < 4; ++kc) {
      const int sb = (kc >> 1) * 32768;
      const int lb = (kc & 1) ? lb1 : lb0;
      bf16x8 lf[4];
#pragma unroll
      for (int nf = 0; nf < 4; ++nf)
        lf[nf] = LDF(pL + sb, nf * 2048, lb);
#pragma unroll
      for (int mf = 0; mf < 2; ++mf) {
        bf16x8 hf = LDF(pH + sb, (mq * 2 + mf) * 2048, lb);
#pragma unroll
        for (int nf = 0; nf < 4; ++nf)
          macc[mf][nf] = __builtin_amdgcn_mfma_f32_16x16x32_bf16(hf, lf[nf], macc[mf][nf], 0, 0, 0);
      }
    }
#pragma unroll
    for (int mf = 0; mf < 2; ++mf)
#pragma unroll
      for (int nf = 0; nf < 4; ++nf) {
        int m8 = mq * 2 + mf;
        uint2 p = pk[m8][nf];
        float t0 = (macc[mf][nf][0] + scl[nf]) * bf2f((u16)(p.x & 0xffff));
        float t1 = (macc[mf][nf][1] + scl[nf]) * bf2f((u16)(p.x >> 16));
        float t2 = (macc[mf][nf][2] + scl[nf]) * bf2f((u16)(p.y & 0xffff));
        float t3 = (macc[mf][nf][3] + scl[nf]) * bf2f((u16)(p.y >> 16));
        p.x = (u32)f2bf(t0) | ((u32)f2bf(t1) << 16);
        p.y = (u32)f2bf(t2) | ((u32)f2bf(t3) << 16);
        pk[m8][nf] = p;
      }
  }

  // restage L2 additive rows over L2m
  __builtin_amdgcn_s_barrier();
  {
    const u16* baseL0 = L2 + (size_t)(OUT_F + bn0) * LRANK;
    const u16* baseL1 = L2 + (size_t)(OUT_F + bn0 + 128) * LRANK;
    STG_L(baseL0,      (char*)lds + 65536);
    STG_L(baseL1,      (char*)lds + 81920);
    STG_L(baseL0 + 64, (char*)lds + 98304);
    STG_L(baseL1 + 64, (char*)lds + 114688);
  }
  asm volatile("s_waitcnt vmcnt(0)" ::: "memory");
  __builtin_amdgcn_s_barrier();

  // additive pass, [2][4] chunks: out = unpack(pk) + maccA + bias
#pragma unroll
  for (int mq = 0; mq < 4; ++mq) {
    f32x4 macc[2][4];
#pragma unroll
    for (int m = 0; m < 2; ++m)
#pragma unroll
      for (int n = 0; n < 4; ++n)
#pragma unroll
        for (int v = 0; v < 4; ++v) macc[m][n][v] = 0.f;
#pragma unroll
    for (int kc = 0; kc < 4; ++kc) {
      const int sb = (kc >> 1) * 32768;
      const int lb = (kc & 1) ? lb1 : lb0;
      bf16x8 lf[4];
#pragma unroll
      for (int nf = 0; nf < 4; ++nf)
        lf[nf] = LDF(pL + sb, nf * 2048, lb);
#pragma unroll
      for (int mf = 0; mf < 2; ++mf) {
        bf16x8 hf = LDF(pH + sb, (mq * 2 + mf) * 2048, lb);
#pragma unroll
        for (int nf = 0; nf < 4; ++nf)
          macc[mf][nf] = __builtin_amdgcn_mfma_f32_16x16x32_bf16(hf, lf[nf], macc[mf][nf], 0, 0, 0);
      }
    }
#pragma unroll
    for (int mf = 0; mf < 2; ++mf)
#pragma unroll
      for (int nf = 0; nf < 4; ++nf) {
        int m8 = mq * 2 + mf;
        uint2 p = pk[m8][nf];
        int rg = bm0 + wg_m * 128 + m8 * 16 + (lane >> 4) * 4;
        int cg = bn0 + wg_n * 64 + nf * 16 + lr;
        float* op = out + (size_t)rg * OUT_F + cg;
        op[0 * OUT_F] = bf2f((u16)(p.x & 0xffff)) + macc[mf][nf][0] + bs_[nf];
        op[1 * OUT_F] = bf2f((u16)(p.x >> 16))    + macc[mf][nf][1] + bs_[nf];
        op[2 * OUT_F] = bf2f((u16)(p.y & 0xffff)) + macc[mf][nf][2] + bs_[nf];
        op[3 * OUT_F] = bf2f((u16)(p.y >> 16))    + macc[mf][nf][3] + bs_[nf];
      }
  }
}

// ---------------- launch ----------------

extern "C" void kernel_launch(void* const* d_in, const int* in_sizes, int n_in,
                              void* d_out, int out_size, void* d_ws, size_t ws_size,
                              hipStream_t stream) {
  const float* input = (const float*)d_in[0];
  const int*   zm    = (const int*)d_in[1];
  const float* cb    = (const float*)d_in[2];
  const float* l1    = (const float*)d_in[3];
  const float* l2    = (const float*)d_in[4];
  const float* gs    = (const float*)d_in[5];
  const float* gb    = (const float*)d_in[6];
  const float* scale = (const float*)d_in[7];
  const float* bias  = (const float*)d_in[8];
  float* out = (float*)d_out;

  const size_t OFF_A  = 0;                                        // 64 MiB
  const size_t OFF_W  = OFF_A + (size_t)NTOK * IN_F * 2;          // 32 MiB
  const size_t OFF_L1 = OFF_W + (size_t)OUT_F * IN_F * 2;         // 1 MiB
  const size_t OFF_L2 = OFF_L1 + (size_t)LRANK * IN_F * 2;        // 2 MiB
  const size_t OFF_H  = OFF_L2 + (size_t)2 * OUT_F * LRANK * 2;   // 2 MiB
  const size_t OFF_HP = OFF_H + (size_t)NTOK * LRANK * 2;         // 32 MiB (f32 partials x8)
  const size_t NEED   = OFF_HP + (size_t)8 * NTOK * LRANK * 4;
  if (ws_size < NEED) return;

  char* ws = (char*)d_ws;
  u16* A    = (u16*)(ws + OFF_A);
  u16* W    = (u16*)(ws + OFF_W);
  u16* L1b  = (u16*)(ws + OFF_L1);
  u16* L2b  = (u16*)(ws + OFF_L2);
  u16* H    = (u16*)(ws + OFF_H);
  float* Hp = (float*)(ws + OFF_HP);

  cvt_bf16_2_kernel<<<((LRANK * IN_F + 2 * OUT_F * LRANK) / 4 + 255) / 256, 256, 0, stream>>>(
      l1, L1b, LRANK * IN_F / 4, l2, L2b, 2 * OUT_F * LRANK / 4);
  dequant_kernel<<<(OUT_F * IN_F / 4) / 256, 256, 0, stream>>>(zm, cb, gs, gb, W);

  hid_part<<<8 * (NTOK / 128), 256, 0, stream>>>(input, A, L1b, Hp);
  hid_reduce<<<(NTOK * LRANK / 4) / 256, 256, 0, stream>>>(Hp, H);

  gemm_main<<<(NTOK / 256) * (OUT_F / 256), 512, 0, stream>>>(A, W, H, L2b, scale, bias, out);
}